// Round 3
// baseline (571.859 us; speedup 1.0000x reference)
//
#include <hip/hip_runtime.h>
#include <math.h>

// Problem constants (fixed by setup_inputs / reference)
#define NU 40000          // n_users
#define NI 20000          // n_items
#define NN 60000          // n_nodes
#define DD 128            // embedding dim
#define NF 4              // factors
#define ME 600000         // M (undirected interactions)
#define NE 1200000        // E = 2*M directed edges
#define NB 4096           // batch

// h/t for edge e:
//  e <  ME : h = row[e],         t = NU + col[e]
//  e >= ME : h = NU + col[e-ME], t = row[e-ME]
// Graph is symmetric: degree-as-head == degree-as-tail.

__device__ __forceinline__ const float* node_row(const float* ue, const float* ie, int n) {
    return (n < NU) ? (ue + (size_t)n * DD) : (ie + (size_t)(n - NU) * DD);
}

// ---------------- CSR build ----------------

__global__ void k_zero(int* counts, int* fill) {
    int i = blockIdx.x * blockDim.x + threadIdx.x;
    if (i < NN) { counts[i] = 0; fill[i] = 0; }
}

__global__ void k_count(const int* __restrict__ row, const int* __restrict__ col,
                        int* __restrict__ counts) {
    int e = blockIdx.x * blockDim.x + threadIdx.x;
    if (e < NE) {
        int h = (e < ME) ? row[e] : (NU + col[e - ME]);
        atomicAdd(&counts[h], 1);
    }
}

// single-block exclusive scan of counts[NN] -> row_ptr[NN+1]
__global__ void k_scan(const int* __restrict__ counts, int* __restrict__ row_ptr) {
    __shared__ int part[1024];
    const int T = 1024;
    const int chunk = (NN + T - 1) / T;
    int tid = threadIdx.x;
    int lo = tid * chunk;
    int hi = lo + chunk; if (hi > NN) hi = NN;
    int s = 0;
    for (int i = lo; i < hi; ++i) s += counts[i];
    part[tid] = s;
    __syncthreads();
    for (int off = 1; off < T; off <<= 1) {
        int v = (tid >= off) ? part[tid - off] : 0;   // read BEFORE barrier
        __syncthreads();
        part[tid] += v;
        __syncthreads();
    }
    int run = (tid == 0) ? 0 : part[tid - 1];
    for (int i = lo; i < hi; ++i) { row_ptr[i] = run; run += counts[i]; }
    if (tid == T - 1) row_ptr[NN] = run;   // == NE
}

// Fill CSR payloads. it=0: A==1 -> softmax==0.25 exactly -> deg0 = 0.25*degree,
// so w0[p] = dinv0[t] = rsqrt(max(0.25*counts[t], 1e-8)) computed inline
// (the matching 0.25*dinv0[h] per-node scale cancels inside prop0's l2norm).
__global__ void k_fill(const int* __restrict__ row, const int* __restrict__ col,
                       const int* __restrict__ row_ptr, int* __restrict__ fill,
                       const int* __restrict__ counts,
                       int* __restrict__ t_sorted, float* __restrict__ w0_sorted) {
    int e = blockIdx.x * blockDim.x + threadIdx.x;
    if (e < NE) {
        int h, t;
        if (e < ME) { h = row[e];            t = NU + col[e]; }
        else        { h = NU + col[e - ME];  t = row[e - ME]; }
        int p = row_ptr[h] + atomicAdd(&fill[h], 1);
        t_sorted[p]  = t;
        w0_sorted[p] = 1.0f / sqrtf(fmaxf(0.25f * (float)counts[t], 1e-8f));
    }
}

// ---------------- iteration 0 propagation + fused l2norm + tanh precompute ----
// fnorm[n] = l2norm_per_factor( sum_p w0[p]*ego(t_p) )   (positive scale cancels)
// ttan[n]  = tanh(l2norm_per_factor(ego[n]))
// 4 nodes per 256-thread block; lane covers dims {2*lane, 2*lane+1}; factor=lane>>4.
__global__ void k_prop0_norm(const float* __restrict__ ue, const float* __restrict__ ie,
                             const int* __restrict__ row_ptr, const int* __restrict__ t_sorted,
                             const float* __restrict__ w0,
                             float* __restrict__ fnorm, float* __restrict__ ttan) {
    int n = blockIdx.x * 4 + (threadIdx.x >> 6);
    if (n >= NN) return;
    int lane = threadIdx.x & 63;
    int p0 = row_ptr[n], p1 = row_ptr[n + 1];
    float2 acc = make_float2(0.f, 0.f);
    #pragma unroll 4
    for (int p = p0; p < p1; ++p) {
        int t = t_sorted[p];
        float w = w0[p];
        float2 v = ((const float2*)node_row(ue, ie, t))[lane];
        acc.x += w * v.x;
        acc.y += w * v.y;
    }
    float ss = acc.x * acc.x + acc.y * acc.y;
    #pragma unroll
    for (int m = 1; m < 16; m <<= 1) ss += __shfl_xor(ss, m);
    float inv = 1.0f / fmaxf(sqrtf(ss), 1e-12f);
    size_t base = (size_t)n * DD;
    ((float2*)(fnorm + base))[lane] = make_float2(acc.x * inv, acc.y * inv);

    float2 u = ((const float2*)node_row(ue, ie, n))[lane];
    float s2 = u.x * u.x + u.y * u.y;
    #pragma unroll
    for (int m = 1; m < 16; m <<= 1) s2 += __shfl_xor(s2, m);
    float inv2 = 1.0f / fmaxf(sqrtf(s2), 1e-12f);
    ((float2*)(ttan + base))[lane] = make_float2(tanhf(u.x * inv2), tanhf(u.y * inv2));
}

// ---------------- fused attention + softmax + deg1, per node ----------------
// For node n (h==n for its whole CSR range): fnorm[n] register-resident;
// per edge: gather ttan[t], per-factor dot, softmax over factors
// (softmax(1+d)==softmax(d)), write normA[p], accumulate deg1 in-register.
__global__ void k_attn_deg(const int* __restrict__ row_ptr, const int* __restrict__ t_sorted,
                           const float* __restrict__ fnorm, const float* __restrict__ ttan,
                           float4* __restrict__ normA, float4* __restrict__ dinv1) {
    int n = blockIdx.x * 4 + (threadIdx.x >> 6);
    if (n >= NN) return;
    int lane = threadIdx.x & 63;
    int p0 = row_ptr[n], p1 = row_ptr[n + 1];
    float2 a = ((const float2*)(fnorm + (size_t)n * DD))[lane];
    float4 deg = make_float4(0.f, 0.f, 0.f, 0.f);
    #pragma unroll 2
    for (int p = p0; p < p1; ++p) {
        int t = t_sorted[p];
        float2 b = ((const float2*)(ttan + (size_t)t * DD))[lane];
        float s = a.x * b.x + a.y * b.y;          // factor = lane>>4
        #pragma unroll
        for (int m = 1; m < 16; m <<= 1) s += __shfl_xor(s, m);
        float d0 = __shfl(s, 0),  d1 = __shfl(s, 16);
        float d2 = __shfl(s, 32), d3 = __shfl(s, 48);
        float mx = fmaxf(fmaxf(d0, d1), fmaxf(d2, d3));
        float e0 = __expf(d0 - mx), e1 = __expf(d1 - mx);
        float e2 = __expf(d2 - mx), e3 = __expf(d3 - mx);
        float inv = 1.0f / (e0 + e1 + e2 + e3);
        e0 *= inv; e1 *= inv; e2 *= inv; e3 *= inv;
        if (lane == 0) normA[p] = make_float4(e0, e1, e2, e3);
        deg.x += e0; deg.y += e1; deg.z += e2; deg.w += e3;
    }
    if (lane == 0) {
        dinv1[n] = make_float4(1.0f / sqrtf(fmaxf(deg.x, 1e-8f)),
                               1.0f / sqrtf(fmaxf(deg.y, 1e-8f)),
                               1.0f / sqrtf(fmaxf(deg.z, 1e-8f)),
                               1.0f / sqrtf(fmaxf(deg.w, 1e-8f)));
    }
}

// ---------------- fused iteration-1 propagation + output, batch rows only ----
// out[r] = 0.5*( ego0[n] + dinv1[n][f] * sum_p normA[p][f]*dinv1[t][f]*ego0(t) )
// Only the 12288 output rows are propagated (~22% of edges vs all-node prop).
__global__ void k_prop1_out(const float* __restrict__ ue, const float* __restrict__ ie,
                            const int* __restrict__ row_ptr, const int* __restrict__ t_sorted,
                            const float* __restrict__ normA, const float* __restrict__ dinv1,
                            const int* __restrict__ users, const int* __restrict__ pos,
                            const int* __restrict__ neg, float* __restrict__ out) {
    int r = blockIdx.x * 4 + (threadIdx.x >> 6);
    if (r >= 3 * NB) return;
    int lane = threadIdx.x & 63;
    int which = r >> 12;
    int i = r & 4095;
    int n;
    if (which == 0)      n = users[i];
    else if (which == 1) n = NU + pos[i];
    else                 n = NU + neg[i];
    int f = lane >> 4;
    int p0 = row_ptr[n], p1 = row_ptr[n + 1];
    float2 acc = make_float2(0.f, 0.f);
    #pragma unroll 4
    for (int p = p0; p < p1; ++p) {
        int t = t_sorted[p];
        float w = normA[(size_t)p * 4 + f] * dinv1[(size_t)t * 4 + f];
        float2 v = ((const float2*)node_row(ue, ie, t))[lane];
        acc.x += w * v.x;
        acc.y += w * v.y;
    }
    float dn = dinv1[(size_t)n * 4 + f];
    float2 e0 = ((const float2*)node_row(ue, ie, n))[lane];
    ((float2*)(out + (size_t)r * DD))[lane] =
        make_float2(0.5f * (e0.x + dn * acc.x), 0.5f * (e0.y + dn * acc.y));
}

// ---------------- launch ----------------

extern "C" void kernel_launch(void* const* d_in, const int* in_sizes, int n_in,
                              void* d_out, int out_size, void* d_ws, size_t ws_size,
                              hipStream_t stream) {
    const float* ue   = (const float*)d_in[0];
    const float* ie   = (const float*)d_in[1];
    const int* row    = (const int*)d_in[2];
    const int* col    = (const int*)d_in[3];
    const int* users  = (const int*)d_in[4];
    const int* pos    = (const int*)d_in[5];
    const int* neg    = (const int*)d_in[6];
    float* out        = (float*)d_out;

    // workspace layout (256B-aligned); total ~92 MB
    char* ws = (char*)d_ws;
    size_t off = 0;
    auto take = [&](size_t bytes) { void* p = ws + off; off += (bytes + 255) & ~(size_t)255; return p; };
    float* fnorm    = (float*)take((size_t)NN * DD * 4);   // 30.72 MB
    float* ttan     = (float*)take((size_t)NN * DD * 4);   // 30.72 MB
    float* normA    = (float*)take((size_t)NE * 4 * 4);    // 19.2 MB
    float* dinv1    = (float*)take((size_t)NN * 4 * 4);    // 0.96 MB
    int*   row_ptr  = (int*)take((size_t)(NN + 1) * 4);
    int*   counts   = (int*)take((size_t)NN * 4);
    int*   fill     = (int*)take((size_t)NN * 4);
    int*   t_sorted = (int*)take((size_t)NE * 4);          // 4.8 MB
    float* w0s      = (float*)take((size_t)NE * 4);        // 4.8 MB
    if (off > ws_size) return;  // workspace too small -> validation flags loudly

    // CSR build
    k_zero <<<(NN + 255) / 256, 256, 0, stream>>>(counts, fill);
    k_count<<<(NE + 255) / 256, 256, 0, stream>>>(row, col, counts);
    k_scan <<<1, 1024, 0, stream>>>(counts, row_ptr);
    k_fill <<<(NE + 255) / 256, 256, 0, stream>>>(row, col, row_ptr, fill, counts,
                                                  t_sorted, w0s);
    // iteration 0 propagation + fused per-factor l2norm + tanh precompute
    k_prop0_norm<<<(NN + 3) / 4, 256, 0, stream>>>(ue, ie, row_ptr, t_sorted, w0s,
                                                   fnorm, ttan);
    // fused attention + softmax + deg1 (per node; fnorm row in registers)
    k_attn_deg<<<(NN + 3) / 4, 256, 0, stream>>>(row_ptr, t_sorted, fnorm, ttan,
                                                 (float4*)normA, (float4*)dinv1);
    // fused iteration-1 propagation + mean + gather, batch rows only
    k_prop1_out<<<(3 * NB) / 4, 256, 0, stream>>>(ue, ie, row_ptr, t_sorted,
                                                  normA, (const float*)dinv1,
                                                  users, pos, neg, out);
}

// Round 5
// 447.194 us; speedup vs baseline: 1.2788x; 1.2788x over previous
//
#include <hip/hip_runtime.h>
#include <hip/hip_fp16.h>
#include <math.h>

// Problem constants (fixed by setup_inputs / reference)
#define NU 40000          // n_users
#define NI 20000          // n_items
#define NN 60000          // n_nodes
#define DD 128            // embedding dim
#define NF 4              // factors
#define ME 600000         // M (undirected interactions)
#define NE 1200000        // E = 2*M directed edges
#define NB 4096           // batch

// h/t for edge e:
//  e <  ME : h = row[e],         t = NU + col[e]
//  e >= ME : h = NU + col[e-ME], t = row[e-ME]
// Graph is symmetric: degree-as-head == degree-as-tail.

__device__ __forceinline__ const float* node_row(const float* ue, const float* ie, int n) {
    return (n < NU) ? (ue + (size_t)n * DD) : (ie + (size_t)(n - NU) * DD);
}

// ---------------- CSR build ----------------

__global__ void k_zero(int* counts, int* fill) {
    int i = blockIdx.x * blockDim.x + threadIdx.x;
    if (i < NN) { counts[i] = 0; fill[i] = 0; }
}

__global__ void k_count(const int* __restrict__ row, const int* __restrict__ col,
                        int* __restrict__ counts) {
    int e = blockIdx.x * blockDim.x + threadIdx.x;
    if (e < NE) {
        int h = (e < ME) ? row[e] : (NU + col[e - ME]);
        atomicAdd(&counts[h], 1);
    }
}

// single-block exclusive scan of counts[NN] -> row_ptr[NN+1]
__global__ void k_scan(const int* __restrict__ counts, int* __restrict__ row_ptr) {
    __shared__ int part[1024];
    const int T = 1024;
    const int chunk = (NN + T - 1) / T;
    int tid = threadIdx.x;
    int lo = tid * chunk;
    int hi = lo + chunk; if (hi > NN) hi = NN;
    int s = 0;
    for (int i = lo; i < hi; ++i) s += counts[i];
    part[tid] = s;
    __syncthreads();
    for (int off = 1; off < T; off <<= 1) {
        int v = (tid >= off) ? part[tid - off] : 0;   // read BEFORE barrier
        __syncthreads();
        part[tid] += v;
        __syncthreads();
    }
    int run = (tid == 0) ? 0 : part[tid - 1];
    for (int i = lo; i < hi; ++i) { row_ptr[i] = run; run += counts[i]; }
    if (tid == T - 1) row_ptr[NN] = run;   // == NE
}

// Fill CSR payloads. it=0: A==1 -> softmax==0.25 exactly -> deg0 = 0.25*degree,
// so w0[p] = dinv0[t] = rsqrt(max(0.25*counts[t], 1e-8)) computed inline
// (the matching 0.25*dinv0[h] per-node scale cancels inside prop0's l2norm).
__global__ void k_fill(const int* __restrict__ row, const int* __restrict__ col,
                       const int* __restrict__ row_ptr, int* __restrict__ fill,
                       const int* __restrict__ counts,
                       int* __restrict__ t_sorted, float* __restrict__ w0_sorted) {
    int e = blockIdx.x * blockDim.x + threadIdx.x;
    if (e < NE) {
        int h, t;
        if (e < ME) { h = row[e];            t = NU + col[e]; }
        else        { h = NU + col[e - ME];  t = row[e - ME]; }
        int p = row_ptr[h] + atomicAdd(&fill[h], 1);
        t_sorted[p]  = t;
        w0_sorted[p] = 1.0f / sqrtf(fmaxf(0.25f * (float)counts[t], 1e-8f));
    }
}

// ---------------- fp16 copy of the embedding table (node-indexed) ----------
// Feeds ONLY the attention chain (fe -> l2norm -> A); final output path stays f32.
__global__ void k_tohalf(const float* __restrict__ src, __half* __restrict__ dst, int n8) {
    int i = blockIdx.x * blockDim.x + threadIdx.x;
    if (i < n8) {
        float4 a = ((const float4*)src)[2 * i];
        float4 b = ((const float4*)src)[2 * i + 1];
        __half2 h[4] = { __floats2half2_rn(a.x, a.y), __floats2half2_rn(a.z, a.w),
                         __floats2half2_rn(b.x, b.y), __floats2half2_rn(b.z, b.w) };
        ((float4*)dst)[i] = *(float4*)h;   // 8 halves = 16 B
    }
}

// ---------------- iteration 0 propagation + fused l2norm + tanh precompute ----
// 32 lanes per node (2 nodes/wave, 8 nodes/block). Lane j covers dims 4j..4j+3.
// Gathers ego16 (fp16) -- result only drives attention weights.
// fnorm[n] = l2norm_per_factor( sum_p w0[p]*ego16(t_p) )  (positive scale cancels)
// ttan[n]  = tanh(l2norm_per_factor(ego[n]))  stored fp16.
__global__ void k_prop0_norm(const float* __restrict__ ue, const float* __restrict__ ie,
                             const __half* __restrict__ ego16,
                             const int* __restrict__ row_ptr, const int* __restrict__ t_sorted,
                             const float* __restrict__ w0,
                             float* __restrict__ fnorm, __half* __restrict__ ttan) {
    int n = blockIdx.x * 8 + (threadIdx.x >> 5);
    if (n >= NN) return;
    int j = threadIdx.x & 31;
    int p0 = row_ptr[n], p1 = row_ptr[n + 1];
    float4 acc = make_float4(0.f, 0.f, 0.f, 0.f);
    #pragma unroll 4
    for (int p = p0; p < p1; ++p) {
        int t = t_sorted[p];
        float w = w0[p];
        float2 raw = ((const float2*)(ego16 + (size_t)t * DD))[j];   // 4 halves
        float2 v01 = __half22float2(*(const __half2*)&raw.x);
        float2 v23 = __half22float2(*(const __half2*)&raw.y);
        acc.x += w * v01.x; acc.y += w * v01.y;
        acc.z += w * v23.x; acc.w += w * v23.y;
    }
    float ss = acc.x * acc.x + acc.y * acc.y + acc.z * acc.z + acc.w * acc.w;
    ss += __shfl_xor(ss, 1); ss += __shfl_xor(ss, 2); ss += __shfl_xor(ss, 4);
    float inv = 1.0f / fmaxf(sqrtf(ss), 1e-12f);
    ((float4*)(fnorm + (size_t)n * DD))[j] =
        make_float4(acc.x * inv, acc.y * inv, acc.z * inv, acc.w * inv);

    float4 u = ((const float4*)node_row(ue, ie, n))[j];
    float s2 = u.x * u.x + u.y * u.y + u.z * u.z + u.w * u.w;
    s2 += __shfl_xor(s2, 1); s2 += __shfl_xor(s2, 2); s2 += __shfl_xor(s2, 4);
    float inv2 = 1.0f / fmaxf(sqrtf(s2), 1e-12f);
    __half2 t01 = __floats2half2_rn(tanhf(u.x * inv2), tanhf(u.y * inv2));
    __half2 t23 = __floats2half2_rn(tanhf(u.z * inv2), tanhf(u.w * inv2));
    __half2 pair[2] = { t01, t23 };
    ((float2*)(ttan + (size_t)n * DD))[j] = *(float2*)pair;          // 4 halves
}

// ---------------- fused attention + softmax + deg1, per node ----------------
// One wave per node; 16 lanes per edge -> 4 edges in flight per iteration.
// il = lane&15 covers dims 8*il..8*il+7 (one fp16 dwordx4), factor f = il>>2.
// Cross-lane ops per 4 edges: 2 (dot) + 2 (max) + 2 (sum) shfl_xor; 1 exp/lane.
__global__ void k_attn_deg(const int* __restrict__ row_ptr, const int* __restrict__ t_sorted,
                           const float* __restrict__ fnorm, const __half* __restrict__ ttan,
                           float* __restrict__ normA, float* __restrict__ dinv1) {
    int n = blockIdx.x * 4 + (threadIdx.x >> 6);
    if (n >= NN) return;
    int lane = threadIdx.x & 63;
    int g  = lane >> 4;        // edge group 0..3
    int il = lane & 15;        // lane within edge
    int f  = il >> 2;          // this lane's factor
    int p0 = row_ptr[n], p1 = row_ptr[n + 1];
    const float4* fn = (const float4*)(fnorm + (size_t)n * DD);
    float4 a0 = fn[2 * il], a1 = fn[2 * il + 1];   // register-resident h-row slice
    float dacc = 0.0f;
    #pragma unroll 2
    for (int pb = p0; pb < p1; pb += 4) {
        int p = pb + g;
        bool valid = p < p1;
        int pc = valid ? p : (p1 - 1);             // clamp: always a real edge
        int t = t_sorted[pc];
        float4 raw = ((const float4*)(ttan + (size_t)t * DD))[il];   // 8 halves
        float2 b0 = __half22float2(*(const __half2*)&raw.x);
        float2 b1 = __half22float2(*(const __half2*)&raw.y);
        float2 b2 = __half22float2(*(const __half2*)&raw.z);
        float2 b3 = __half22float2(*(const __half2*)&raw.w);
        float s = a0.x * b0.x + a0.y * b0.y + a0.z * b1.x + a0.w * b1.y
                + a1.x * b2.x + a1.y * b2.y + a1.z * b3.x + a1.w * b3.y;
        s += __shfl_xor(s, 1);
        s += __shfl_xor(s, 2);                     // 4 lanes of factor f share s_f
        float m1 = fmaxf(s, __shfl_xor(s, 4));
        float mx = fmaxf(m1, __shfl_xor(m1, 8));   // max over 4 factors
        float e = __expf(s - mx);
        float sum = e;
        sum += __shfl_xor(sum, 4);
        sum += __shfl_xor(sum, 8);                 // sum over 4 factors
        float v = e * __builtin_amdgcn_rcpf(sum);  // softmaxed A for factor f
        if (valid) {
            if ((il & 3) == 0) normA[(size_t)pc * 4 + f] = v;
            dacc += v;
        }
    }
    // sum deg over the 4 edge-groups (lane position preserved)
    dacc += __shfl_xor(dacc, 16);
    dacc += __shfl_xor(dacc, 32);
    if (g == 0 && (il & 3) == 0)
        dinv1[(size_t)n * 4 + f] = 1.0f / sqrtf(fmaxf(dacc, 1e-8f));
}

// ---------------- fused iteration-1 propagation + output, batch rows only ----
// out[r] = 0.5*( ego0[n] + dinv1[n][f] * sum_p normA[p][f]*dinv1[t][f]*ego0(t) )
// 32 lanes per output row (2 rows/wave); lane j covers dims 4j..4j+3, f=j>>3.
// Pure f32 path (output precision).
__global__ void k_prop1_out(const float* __restrict__ ue, const float* __restrict__ ie,
                            const int* __restrict__ row_ptr, const int* __restrict__ t_sorted,
                            const float* __restrict__ normA, const float* __restrict__ dinv1,
                            const int* __restrict__ users, const int* __restrict__ pos,
                            const int* __restrict__ neg, float* __restrict__ out) {
    int r = blockIdx.x * 8 + (threadIdx.x >> 5);
    if (r >= 3 * NB) return;
    int j = threadIdx.x & 31;
    int f = j >> 3;
    int which = r >> 12;
    int i = r & 4095;
    int n;
    if (which == 0)      n = users[i];
    else if (which == 1) n = NU + pos[i];
    else                 n = NU + neg[i];
    int p0 = row_ptr[n], p1 = row_ptr[n + 1];
    float4 acc = make_float4(0.f, 0.f, 0.f, 0.f);
    #pragma unroll 4
    for (int p = p0; p < p1; ++p) {
        int t = t_sorted[p];
        float w = normA[(size_t)p * 4 + f] * dinv1[(size_t)t * 4 + f];
        float4 v = ((const float4*)node_row(ue, ie, t))[j];
        acc.x += w * v.x; acc.y += w * v.y;
        acc.z += w * v.z; acc.w += w * v.w;
    }
    float dn = dinv1[(size_t)n * 4 + f];
    float4 e0 = ((const float4*)node_row(ue, ie, n))[j];
    ((float4*)(out + (size_t)r * DD))[j] =
        make_float4(0.5f * (e0.x + dn * acc.x), 0.5f * (e0.y + dn * acc.y),
                    0.5f * (e0.z + dn * acc.z), 0.5f * (e0.w + dn * acc.w));
}

// ---------------- launch ----------------

extern "C" void kernel_launch(void* const* d_in, const int* in_sizes, int n_in,
                              void* d_out, int out_size, void* d_ws, size_t ws_size,
                              hipStream_t stream) {
    const float* ue   = (const float*)d_in[0];
    const float* ie   = (const float*)d_in[1];
    const int* row    = (const int*)d_in[2];
    const int* col    = (const int*)d_in[3];
    const int* users  = (const int*)d_in[4];
    const int* pos    = (const int*)d_in[5];
    const int* neg    = (const int*)d_in[6];
    float* out        = (float*)d_out;

    // workspace layout (256B-aligned); total ~92 MB
    char* ws = (char*)d_ws;
    size_t off = 0;
    auto take = [&](size_t bytes) { void* p = ws + off; off += (bytes + 255) & ~(size_t)255; return p; };
    float*  fnorm    = (float*)take((size_t)NN * DD * 4);    // 30.72 MB
    __half* ttan     = (__half*)take((size_t)NN * DD * 2);   // 15.36 MB (fp16)
    __half* ego16    = (__half*)take((size_t)NN * DD * 2);   // 15.36 MB (fp16)
    float*  normA    = (float*)take((size_t)NE * 4 * 4);     // 19.2 MB
    float*  dinv1    = (float*)take((size_t)NN * 4 * 4);     // 0.96 MB
    int*    row_ptr  = (int*)take((size_t)(NN + 1) * 4);
    int*    counts   = (int*)take((size_t)NN * 4);
    int*    fill     = (int*)take((size_t)NN * 4);
    int*    t_sorted = (int*)take((size_t)NE * 4);           // 4.8 MB
    float*  w0s      = (float*)take((size_t)NE * 4);         // 4.8 MB
    if (off > ws_size) return;  // workspace too small -> validation flags loudly

    // CSR build (+ fp16 embedding copy, independent -> overlaps in graph replay)
    k_zero <<<(NN + 255) / 256, 256, 0, stream>>>(counts, fill);
    k_count<<<(NE + 255) / 256, 256, 0, stream>>>(row, col, counts);
    k_tohalf<<<((NU * DD / 8) + 255) / 256, 256, 0, stream>>>(ue, ego16, NU * DD / 8);
    k_tohalf<<<((NI * DD / 8) + 255) / 256, 256, 0, stream>>>(ie, ego16 + (size_t)NU * DD, NI * DD / 8);
    k_scan <<<1, 1024, 0, stream>>>(counts, row_ptr);
    k_fill <<<(NE + 255) / 256, 256, 0, stream>>>(row, col, row_ptr, fill, counts,
                                                  t_sorted, w0s);
    // iteration 0 propagation (fp16 gather) + fused l2norm + tanh precompute
    k_prop0_norm<<<(NN + 7) / 8, 256, 0, stream>>>(ue, ie, ego16, row_ptr, t_sorted,
                                                   w0s, fnorm, ttan);
    // fused attention + softmax + deg1 (4 edges in flight per wave, fp16 gather)
    k_attn_deg<<<(NN + 3) / 4, 256, 0, stream>>>(row_ptr, t_sorted, fnorm, ttan,
                                                 normA, (float*)dinv1);
    // fused iteration-1 propagation + mean + gather, batch rows only (f32 path)
    k_prop1_out<<<(3 * NB) / 8, 256, 0, stream>>>(ue, ie, row_ptr, t_sorted,
                                                  normA, (const float*)dinv1,
                                                  users, pos, neg, out);
}

// Round 6
// 361.221 us; speedup vs baseline: 1.5831x; 1.2380x over previous
//
#include <hip/hip_runtime.h>
#include <hip/hip_fp16.h>
#include <math.h>

// Problem constants (fixed by setup_inputs / reference)
#define NU 40000          // n_users
#define NI 20000          // n_items
#define NN 60000          // n_nodes
#define DD 128            // embedding dim
#define NF 4              // factors
#define ME 600000         // M (undirected interactions)
#define NE 1200000        // E = 2*M directed edges
#define NB 4096           // batch
#define NBLK 235          // ceil(NN/256) for the scan

// h/t for edge e:
//  e <  ME : h = row[e],         t = NU + col[e]
//  e >= ME : h = NU + col[e-ME], t = row[e-ME]
// Graph is symmetric: degree-as-head == degree-as-tail.

__device__ __forceinline__ const float* node_row(const float* ue, const float* ie, int n) {
    return (n < NU) ? (ue + (size_t)n * DD) : (ie + (size_t)(n - NU) * DD);
}

// ---------------- CSR build ----------------

__global__ void k_zero(int* counts) {
    int i = blockIdx.x * blockDim.x + threadIdx.x;
    if (i < NN) counts[i] = 0;
}

__global__ void k_count(const int* __restrict__ row, const int* __restrict__ col,
                        int* __restrict__ counts) {
    int e = blockIdx.x * blockDim.x + threadIdx.x;
    if (e < NE) {
        int h = (e < ME) ? row[e] : (NU + col[e - ME]);
        atomicAdd(&counts[h], 1);
    }
}

// ---- hierarchical exclusive scan: A (per-block), B (block sums), C (apply) ----

__global__ void k_scanA(const int* __restrict__ counts, int* __restrict__ pre,
                        int* __restrict__ bsum) {
    int tid = threadIdx.x;
    int i = blockIdx.x * 256 + tid;
    int v = (i < NN) ? counts[i] : 0;
    int lane = tid & 63, w = tid >> 6;
    int s = v;
    #pragma unroll
    for (int off = 1; off < 64; off <<= 1) {
        int o = __shfl_up(s, off);
        if (lane >= off) s += o;
    }
    __shared__ int wsum[4];
    if (lane == 63) wsum[w] = s;
    __syncthreads();
    int add = 0;
    #pragma unroll
    for (int k = 0; k < 4; ++k) add += (k < w) ? wsum[k] : 0;
    if (i < NN) pre[i] = s - v + add;              // block-local exclusive
    if (tid == 255) bsum[blockIdx.x] = add + s;    // block total
}

__global__ void k_scanB(const int* __restrict__ bsum, int* __restrict__ boff) {
    int tid = threadIdx.x;                          // one block of 256
    int v = (tid < NBLK) ? bsum[tid] : 0;
    int lane = tid & 63, w = tid >> 6;
    int s = v;
    #pragma unroll
    for (int off = 1; off < 64; off <<= 1) {
        int o = __shfl_up(s, off);
        if (lane >= off) s += o;
    }
    __shared__ int wsum[4];
    if (lane == 63) wsum[w] = s;
    __syncthreads();
    int add = 0;
    #pragma unroll
    for (int k = 0; k < 4; ++k) add += (k < w) ? wsum[k] : 0;
    if (tid < NBLK) boff[tid] = s - v + add;
}

// apply block offsets; also emit cursor copy (for fill) and dinv0 table
__global__ void k_scanC(const int* __restrict__ pre, const int* __restrict__ boff,
                        const int* __restrict__ counts,
                        int* __restrict__ row_ptr, int* __restrict__ cursor,
                        float* __restrict__ dinv0) {
    int i = blockIdx.x * 256 + threadIdx.x;
    if (i < NN) {
        int v = pre[i] + boff[blockIdx.x];
        row_ptr[i] = v;
        cursor[i]  = v;
        dinv0[i]   = 1.0f / sqrtf(fmaxf(0.25f * (float)counts[i], 1e-8f));
    }
    if (i == 0) row_ptr[NN] = NE;
}

// Fill CSR adjacency: single 4B scatter per edge, single atomic on cursor.
__global__ void k_fill(const int* __restrict__ row, const int* __restrict__ col,
                       int* __restrict__ cursor, int* __restrict__ t_sorted) {
    int e = blockIdx.x * blockDim.x + threadIdx.x;
    if (e < NE) {
        int h, t;
        if (e < ME) { h = row[e];            t = NU + col[e]; }
        else        { h = NU + col[e - ME];  t = row[e - ME]; }
        int p = atomicAdd(&cursor[h], 1);
        t_sorted[p] = t;
    }
}

// ---------------- fp16 copy of the embedding table (node-indexed) ----------
// Feeds ONLY the attention chain (fe -> l2norm -> A); final output path stays f32.
__global__ void k_tohalf(const float* __restrict__ src, __half* __restrict__ dst, int n8) {
    int i = blockIdx.x * blockDim.x + threadIdx.x;
    if (i < n8) {
        float4 a = ((const float4*)src)[2 * i];
        float4 b = ((const float4*)src)[2 * i + 1];
        __half2 h[4] = { __floats2half2_rn(a.x, a.y), __floats2half2_rn(a.z, a.w),
                         __floats2half2_rn(b.x, b.y), __floats2half2_rn(b.z, b.w) };
        ((float4*)dst)[i] = *(float4*)h;   // 8 halves = 16 B
    }
}

// ---------------- iteration 0 propagation + fused l2norm + tanh precompute ----
// 32 lanes per node (2 nodes/wave, 8 nodes/block). Lane j covers dims 4j..4j+3.
// Gathers ego16 (fp16) + dinv0[t] (240KB L2-resident table).
// fnorm[n] = l2norm_per_factor( sum_p dinv0[t_p]*ego16(t_p) ) (pos. scale cancels)
// ttan[n]  = tanh(l2norm_per_factor(ego[n]))  stored fp16.
__global__ void k_prop0_norm(const float* __restrict__ ue, const float* __restrict__ ie,
                             const __half* __restrict__ ego16,
                             const int* __restrict__ row_ptr, const int* __restrict__ t_sorted,
                             const float* __restrict__ dinv0,
                             float* __restrict__ fnorm, __half* __restrict__ ttan) {
    int n = blockIdx.x * 8 + (threadIdx.x >> 5);
    if (n >= NN) return;
    int j = threadIdx.x & 31;
    int p0 = row_ptr[n], p1 = row_ptr[n + 1];
    float4 acc = make_float4(0.f, 0.f, 0.f, 0.f);
    #pragma unroll 4
    for (int p = p0; p < p1; ++p) {
        int t = t_sorted[p];
        float w = dinv0[t];
        float2 raw = ((const float2*)(ego16 + (size_t)t * DD))[j];   // 4 halves
        float2 v01 = __half22float2(*(const __half2*)&raw.x);
        float2 v23 = __half22float2(*(const __half2*)&raw.y);
        acc.x += w * v01.x; acc.y += w * v01.y;
        acc.z += w * v23.x; acc.w += w * v23.y;
    }
    float ss = acc.x * acc.x + acc.y * acc.y + acc.z * acc.z + acc.w * acc.w;
    ss += __shfl_xor(ss, 1); ss += __shfl_xor(ss, 2); ss += __shfl_xor(ss, 4);
    float inv = 1.0f / fmaxf(sqrtf(ss), 1e-12f);
    ((float4*)(fnorm + (size_t)n * DD))[j] =
        make_float4(acc.x * inv, acc.y * inv, acc.z * inv, acc.w * inv);

    float4 u = ((const float4*)node_row(ue, ie, n))[j];
    float s2 = u.x * u.x + u.y * u.y + u.z * u.z + u.w * u.w;
    s2 += __shfl_xor(s2, 1); s2 += __shfl_xor(s2, 2); s2 += __shfl_xor(s2, 4);
    float inv2 = 1.0f / fmaxf(sqrtf(s2), 1e-12f);
    __half2 t01 = __floats2half2_rn(tanhf(u.x * inv2), tanhf(u.y * inv2));
    __half2 t23 = __floats2half2_rn(tanhf(u.z * inv2), tanhf(u.w * inv2));
    __half2 pair[2] = { t01, t23 };
    ((float2*)(ttan + (size_t)n * DD))[j] = *(float2*)pair;          // 4 halves
}

// ---------------- fused attention + softmax + deg1, per node ----------------
// One wave per node; 16 lanes per edge -> 4 edges in flight per iteration.
// il = lane&15 covers dims 8*il..8*il+7 (one fp16 dwordx4), factor f = il>>2.
// Cross-lane ops per 4 edges: 2 (dot) + 2 (max) + 2 (sum) shfl_xor; 1 exp/lane.
__global__ void k_attn_deg(const int* __restrict__ row_ptr, const int* __restrict__ t_sorted,
                           const float* __restrict__ fnorm, const __half* __restrict__ ttan,
                           float* __restrict__ normA, float* __restrict__ dinv1) {
    int n = blockIdx.x * 4 + (threadIdx.x >> 6);
    if (n >= NN) return;
    int lane = threadIdx.x & 63;
    int g  = lane >> 4;        // edge group 0..3
    int il = lane & 15;        // lane within edge
    int f  = il >> 2;          // this lane's factor
    int p0 = row_ptr[n], p1 = row_ptr[n + 1];
    const float4* fn = (const float4*)(fnorm + (size_t)n * DD);
    float4 a0 = fn[2 * il], a1 = fn[2 * il + 1];   // register-resident h-row slice
    float dacc = 0.0f;
    #pragma unroll 2
    for (int pb = p0; pb < p1; pb += 4) {
        int p = pb + g;
        bool valid = p < p1;
        int pc = valid ? p : (p1 - 1);             // clamp: always a real edge
        int t = t_sorted[pc];
        float4 raw = ((const float4*)(ttan + (size_t)t * DD))[il];   // 8 halves
        float2 b0 = __half22float2(*(const __half2*)&raw.x);
        float2 b1 = __half22float2(*(const __half2*)&raw.y);
        float2 b2 = __half22float2(*(const __half2*)&raw.z);
        float2 b3 = __half22float2(*(const __half2*)&raw.w);
        float s = a0.x * b0.x + a0.y * b0.y + a0.z * b1.x + a0.w * b1.y
                + a1.x * b2.x + a1.y * b2.y + a1.z * b3.x + a1.w * b3.y;
        s += __shfl_xor(s, 1);
        s += __shfl_xor(s, 2);                     // 4 lanes of factor f share s_f
        float m1 = fmaxf(s, __shfl_xor(s, 4));
        float mx = fmaxf(m1, __shfl_xor(m1, 8));   // max over 4 factors
        float e = __expf(s - mx);
        float sum = e;
        sum += __shfl_xor(sum, 4);
        sum += __shfl_xor(sum, 8);                 // sum over 4 factors
        float v = e * __builtin_amdgcn_rcpf(sum);  // softmaxed A for factor f
        if (valid) {
            if ((il & 3) == 0) normA[(size_t)pc * 4 + f] = v;
            dacc += v;
        }
    }
    // sum deg over the 4 edge-groups (lane position preserved)
    dacc += __shfl_xor(dacc, 16);
    dacc += __shfl_xor(dacc, 32);
    if (g == 0 && (il & 3) == 0)
        dinv1[(size_t)n * 4 + f] = 1.0f / sqrtf(fmaxf(dacc, 1e-8f));
}

// ---------------- fused iteration-1 propagation + output, batch rows only ----
// out[r] = 0.5*( ego0[n] + dinv1[n][f] * sum_p normA[p][f]*dinv1[t][f]*ego0(t) )
// 32 lanes per output row (2 rows/wave); lane j covers dims 4j..4j+3, f=j>>3.
// Pure f32 path (output precision).
__global__ void k_prop1_out(const float* __restrict__ ue, const float* __restrict__ ie,
                            const int* __restrict__ row_ptr, const int* __restrict__ t_sorted,
                            const float* __restrict__ normA, const float* __restrict__ dinv1,
                            const int* __restrict__ users, const int* __restrict__ pos,
                            const int* __restrict__ neg, float* __restrict__ out) {
    int r = blockIdx.x * 8 + (threadIdx.x >> 5);
    if (r >= 3 * NB) return;
    int j = threadIdx.x & 31;
    int f = j >> 3;
    int which = r >> 12;
    int i = r & 4095;
    int n;
    if (which == 0)      n = users[i];
    else if (which == 1) n = NU + pos[i];
    else                 n = NU + neg[i];
    int p0 = row_ptr[n], p1 = row_ptr[n + 1];
    float4 acc = make_float4(0.f, 0.f, 0.f, 0.f);
    #pragma unroll 4
    for (int p = p0; p < p1; ++p) {
        int t = t_sorted[p];
        float w = normA[(size_t)p * 4 + f] * dinv1[(size_t)t * 4 + f];
        float4 v = ((const float4*)node_row(ue, ie, t))[j];
        acc.x += w * v.x; acc.y += w * v.y;
        acc.z += w * v.z; acc.w += w * v.w;
    }
    float dn = dinv1[(size_t)n * 4 + f];
    float4 e0 = ((const float4*)node_row(ue, ie, n))[j];
    ((float4*)(out + (size_t)r * DD))[j] =
        make_float4(0.5f * (e0.x + dn * acc.x), 0.5f * (e0.y + dn * acc.y),
                    0.5f * (e0.z + dn * acc.z), 0.5f * (e0.w + dn * acc.w));
}

// ---------------- launch ----------------

extern "C" void kernel_launch(void* const* d_in, const int* in_sizes, int n_in,
                              void* d_out, int out_size, void* d_ws, size_t ws_size,
                              hipStream_t stream) {
    const float* ue   = (const float*)d_in[0];
    const float* ie   = (const float*)d_in[1];
    const int* row    = (const int*)d_in[2];
    const int* col    = (const int*)d_in[3];
    const int* users  = (const int*)d_in[4];
    const int* pos    = (const int*)d_in[5];
    const int* neg    = (const int*)d_in[6];
    float* out        = (float*)d_out;

    // workspace layout (256B-aligned); total ~88 MB
    char* ws = (char*)d_ws;
    size_t off = 0;
    auto take = [&](size_t bytes) { void* p = ws + off; off += (bytes + 255) & ~(size_t)255; return p; };
    float*  fnorm    = (float*)take((size_t)NN * DD * 4);    // 30.72 MB
    __half* ttan     = (__half*)take((size_t)NN * DD * 2);   // 15.36 MB (fp16)
    __half* ego16    = (__half*)take((size_t)NN * DD * 2);   // 15.36 MB (fp16)
    float*  normA    = (float*)take((size_t)NE * 4 * 4);     // 19.2 MB
    float*  dinv1    = (float*)take((size_t)NN * 4 * 4);     // 0.96 MB
    float*  dinv0    = (float*)take((size_t)NN * 4);         // 0.24 MB
    int*    row_ptr  = (int*)take((size_t)(NN + 1) * 4);
    int*    counts   = (int*)take((size_t)NN * 4);
    int*    cursor   = (int*)take((size_t)NN * 4);
    int*    pre      = (int*)take((size_t)NN * 4);
    int*    bsum     = (int*)take((size_t)NBLK * 4);
    int*    boff     = (int*)take((size_t)NBLK * 4);
    int*    t_sorted = (int*)take((size_t)NE * 4);           // 4.8 MB
    if (off > ws_size) return;  // workspace too small -> validation flags loudly

    // CSR build (hierarchical scan; fp16 embedding copy interleaved)
    k_zero <<<(NN + 255) / 256, 256, 0, stream>>>(counts);
    k_count<<<(NE + 255) / 256, 256, 0, stream>>>(row, col, counts);
    k_tohalf<<<((NU * DD / 8) + 255) / 256, 256, 0, stream>>>(ue, ego16, NU * DD / 8);
    k_tohalf<<<((NI * DD / 8) + 255) / 256, 256, 0, stream>>>(ie, ego16 + (size_t)NU * DD, NI * DD / 8);
    k_scanA<<<NBLK, 256, 0, stream>>>(counts, pre, bsum);
    k_scanB<<<1, 256, 0, stream>>>(bsum, boff);
    k_scanC<<<NBLK, 256, 0, stream>>>(pre, boff, counts, row_ptr, cursor, dinv0);
    k_fill <<<(NE + 255) / 256, 256, 0, stream>>>(row, col, cursor, t_sorted);
    // iteration 0 propagation (fp16 gather) + fused l2norm + tanh precompute
    k_prop0_norm<<<(NN + 7) / 8, 256, 0, stream>>>(ue, ie, ego16, row_ptr, t_sorted,
                                                   dinv0, fnorm, ttan);
    // fused attention + softmax + deg1 (4 edges in flight per wave, fp16 gather)
    k_attn_deg<<<(NN + 3) / 4, 256, 0, stream>>>(row_ptr, t_sorted, fnorm, ttan,
                                                 normA, (float*)dinv1);
    // fused iteration-1 propagation + mean + gather, batch rows only (f32 path)
    k_prop1_out<<<(3 * NB) / 8, 256, 0, stream>>>(ue, ie, row_ptr, t_sorted,
                                                  normA, (const float*)dinv1,
                                                  users, pos, neg, out);
}

// Round 9
// 289.830 us; speedup vs baseline: 1.9731x; 1.2463x over previous
//
#include <hip/hip_runtime.h>
#include <hip/hip_fp16.h>
#include <math.h>

// Problem constants (fixed by setup_inputs / reference)
#define NU 40000          // n_users
#define NI 20000          // n_items
#define NN 60000          // n_nodes
#define DD 128            // embedding dim
#define NF 4              // factors
#define ME 600000         // M (undirected interactions)
#define NE 1200000        // E = 2*M directed edges
#define NB 4096           // batch
#define NBLK 235          // ceil(NN/256) for the scan
#define CPAD 16           // counter padding: one counter per 64B line

// h/t for edge e:
//  e <  ME : h = row[e],         t = NU + col[e]
//  e >= ME : h = NU + col[e-ME], t = row[e-ME]
// Graph is symmetric: degree-as-head == degree-as-tail.

__device__ __forceinline__ const float* node_row(const float* ue, const float* ie, int n) {
    return (n < NU) ? (ue + (size_t)n * DD) : (ie + (size_t)(n - NU) * DD);
}

// ---------------- CSR build ----------------

__global__ void k_zero(int* counts) {
    int i = blockIdx.x * blockDim.x + threadIdx.x;
    if (i < NN * CPAD) counts[i] = 0;
}

// count + rank assignment (4 edges/thread, int4 loads, padded counters).
// ME % 4 == 0, so a 4-edge block never straddles the h/t formula switch.
__global__ void k_count(const int* __restrict__ row, const int* __restrict__ col,
                        int* __restrict__ counts, int* __restrict__ rank) {
    int base = (blockIdx.x * blockDim.x + threadIdx.x) * 4;
    if (base >= NE) return;
    int4 h4;
    if (base < ME) {
        h4 = *(const int4*)(row + base);
    } else {
        int4 c4 = *(const int4*)(col + (base - ME));
        h4 = make_int4(NU + c4.x, NU + c4.y, NU + c4.z, NU + c4.w);
    }
    int4 r;
    r.x = atomicAdd(&counts[h4.x * CPAD], 1);
    r.y = atomicAdd(&counts[h4.y * CPAD], 1);
    r.z = atomicAdd(&counts[h4.z * CPAD], 1);
    r.w = atomicAdd(&counts[h4.w * CPAD], 1);
    *(int4*)(rank + base) = r;
}

// ---- hierarchical exclusive scan: A (per-block), B (block sums), C (apply) ----

__global__ void k_scanA(const int* __restrict__ counts, int* __restrict__ pre,
                        int* __restrict__ bsum) {
    int tid = threadIdx.x;
    int i = blockIdx.x * 256 + tid;
    int v = (i < NN) ? counts[i * CPAD] : 0;
    int lane = tid & 63, w = tid >> 6;
    int s = v;
    #pragma unroll
    for (int off = 1; off < 64; off <<= 1) {
        int o = __shfl_up(s, off);
        if (lane >= off) s += o;
    }
    __shared__ int wsum[4];
    if (lane == 63) wsum[w] = s;
    __syncthreads();
    int add = 0;
    #pragma unroll
    for (int k = 0; k < 4; ++k) add += (k < w) ? wsum[k] : 0;
    if (i < NN) pre[i] = s - v + add;              // block-local exclusive
    if (tid == 255) bsum[blockIdx.x] = add + s;    // block total
}

__global__ void k_scanB(const int* __restrict__ bsum, int* __restrict__ boff) {
    int tid = threadIdx.x;                          // one block of 256
    int v = (tid < NBLK) ? bsum[tid] : 0;
    int lane = tid & 63, w = tid >> 6;
    int s = v;
    #pragma unroll
    for (int off = 1; off < 64; off <<= 1) {
        int o = __shfl_up(s, off);
        if (lane >= off) s += o;
    }
    __shared__ int wsum[4];
    if (lane == 63) wsum[w] = s;
    __syncthreads();
    int add = 0;
    #pragma unroll
    for (int k = 0; k < 4; ++k) add += (k < w) ? wsum[k] : 0;
    if (tid < NBLK) boff[tid] = s - v + add;
}

// apply block offsets; also emit dinv0 table (deg0 = 0.25*degree)
__global__ void k_scanC(const int* __restrict__ pre, const int* __restrict__ boff,
                        const int* __restrict__ counts,
                        int* __restrict__ row_ptr, float* __restrict__ dinv0) {
    int i = blockIdx.x * 256 + threadIdx.x;
    if (i < NN) {
        row_ptr[i] = pre[i] + boff[blockIdx.x];
        dinv0[i]   = 1.0f / sqrtf(fmaxf(0.25f * (float)counts[i * CPAD], 1e-8f));
    }
    if (i == 0) row_ptr[NN] = NE;
}

// Fill CSR adjacency: ATOMIC-FREE. p = row_ptr[h] + rank[e]; uint16 payload.
__global__ void k_fill(const int* __restrict__ row, const int* __restrict__ col,
                       const int* __restrict__ row_ptr, const int* __restrict__ rank,
                       unsigned short* __restrict__ t_sorted) {
    int base = (blockIdx.x * blockDim.x + threadIdx.x) * 4;
    if (base >= NE) return;
    int4 h4, t4;
    if (base < ME) {
        h4 = *(const int4*)(row + base);
        int4 c4 = *(const int4*)(col + base);
        t4 = make_int4(NU + c4.x, NU + c4.y, NU + c4.z, NU + c4.w);
    } else {
        int4 c4 = *(const int4*)(col + (base - ME));
        h4 = make_int4(NU + c4.x, NU + c4.y, NU + c4.z, NU + c4.w);
        t4 = *(const int4*)(row + (base - ME));
    }
    int4 r = *(const int4*)(rank + base);
    t_sorted[row_ptr[h4.x] + r.x] = (unsigned short)t4.x;
    t_sorted[row_ptr[h4.y] + r.y] = (unsigned short)t4.y;
    t_sorted[row_ptr[h4.z] + r.z] = (unsigned short)t4.z;
    t_sorted[row_ptr[h4.w] + r.w] = (unsigned short)t4.w;
}

// ---------------- fp16 copy of the embedding table (node-indexed) ----------
// Feeds ONLY the attention chain (fe -> l2norm -> A); final output path stays f32.
__global__ void k_tohalf(const float* __restrict__ src, __half* __restrict__ dst, int n8) {
    int i = blockIdx.x * blockDim.x + threadIdx.x;
    if (i < n8) {
        float4 a = ((const float4*)src)[2 * i];
        float4 b = ((const float4*)src)[2 * i + 1];
        __half2 h[4] = { __floats2half2_rn(a.x, a.y), __floats2half2_rn(a.z, a.w),
                         __floats2half2_rn(b.x, b.y), __floats2half2_rn(b.z, b.w) };
        ((float4*)dst)[i] = *(float4*)h;   // 8 halves = 16 B
    }
}

// ---------------- iteration 0 propagation + fused l2norm + tanh precompute ----
// 32 lanes per node (2 nodes/wave, 8 nodes/block). Lane j covers dims 4j..4j+3.
// Gathers ego16 (fp16) + dinv0[t] (240KB L2-resident table).
// fnorm[n] = l2norm_per_factor( sum_p dinv0[t_p]*ego16(t_p) ), stored fp16
// (values <=1; error budget analyzed: ~1e-6 at output).
// ttan[n]  = tanh(l2norm_per_factor(ego[n])), stored fp16.
__global__ void k_prop0_norm(const float* __restrict__ ue, const float* __restrict__ ie,
                             const __half* __restrict__ ego16,
                             const int* __restrict__ row_ptr,
                             const unsigned short* __restrict__ t_sorted,
                             const float* __restrict__ dinv0,
                             __half* __restrict__ fnorm, __half* __restrict__ ttan) {
    int n = blockIdx.x * 8 + (threadIdx.x >> 5);
    if (n >= NN) return;
    int j = threadIdx.x & 31;
    int p0 = row_ptr[n], p1 = row_ptr[n + 1];
    float4 acc = make_float4(0.f, 0.f, 0.f, 0.f);
    #pragma unroll 4
    for (int p = p0; p < p1; ++p) {
        int t = t_sorted[p];
        float w = dinv0[t];
        float2 raw = ((const float2*)(ego16 + (size_t)t * DD))[j];   // 4 halves
        float2 v01 = __half22float2(*(const __half2*)&raw.x);
        float2 v23 = __half22float2(*(const __half2*)&raw.y);
        acc.x += w * v01.x; acc.y += w * v01.y;
        acc.z += w * v23.x; acc.w += w * v23.y;
    }
    float ss = acc.x * acc.x + acc.y * acc.y + acc.z * acc.z + acc.w * acc.w;
    ss += __shfl_xor(ss, 1); ss += __shfl_xor(ss, 2); ss += __shfl_xor(ss, 4);
    float inv = 1.0f / fmaxf(sqrtf(ss), 1e-12f);
    __half2 f01 = __floats2half2_rn(acc.x * inv, acc.y * inv);
    __half2 f23 = __floats2half2_rn(acc.z * inv, acc.w * inv);
    __half2 fpair[2] = { f01, f23 };
    ((float2*)(fnorm + (size_t)n * DD))[j] = *(float2*)fpair;        // 4 halves

    float4 u = ((const float4*)node_row(ue, ie, n))[j];
    float s2 = u.x * u.x + u.y * u.y + u.z * u.z + u.w * u.w;
    s2 += __shfl_xor(s2, 1); s2 += __shfl_xor(s2, 2); s2 += __shfl_xor(s2, 4);
    float inv2 = 1.0f / fmaxf(sqrtf(s2), 1e-12f);
    __half2 t01 = __floats2half2_rn(tanhf(u.x * inv2), tanhf(u.y * inv2));
    __half2 t23 = __floats2half2_rn(tanhf(u.z * inv2), tanhf(u.w * inv2));
    __half2 tpair[2] = { t01, t23 };
    ((float2*)(ttan + (size_t)n * DD))[j] = *(float2*)tpair;         // 4 halves
}

// ---------------- fused attention + softmax + deg1, per node ----------------
// One wave per node; 16 lanes per edge -> 4 edges in flight per iteration.
// il = lane&15 covers dims 8*il..8*il+7 (one fp16 dwordx4), factor f = il>>2.
// Cross-lane ops per 4 edges: 2 (dot) + 2 (max) + 2 (sum) shfl_xor; 1 exp/lane.
__global__ void k_attn_deg(const int* __restrict__ row_ptr,
                           const unsigned short* __restrict__ t_sorted,
                           const __half* __restrict__ fnorm, const __half* __restrict__ ttan,
                           float* __restrict__ normA, float* __restrict__ dinv1) {
    int n = blockIdx.x * 4 + (threadIdx.x >> 6);
    if (n >= NN) return;
    int lane = threadIdx.x & 63;
    int g  = lane >> 4;        // edge group 0..3
    int il = lane & 15;        // lane within edge
    int f  = il >> 2;          // this lane's factor
    int p0 = row_ptr[n], p1 = row_ptr[n + 1];
    float4 rawa = ((const float4*)(fnorm + (size_t)n * DD))[il];     // 8 halves
    float2 a0 = __half22float2(*(const __half2*)&rawa.x);
    float2 a1 = __half22float2(*(const __half2*)&rawa.y);
    float2 a2 = __half22float2(*(const __half2*)&rawa.z);
    float2 a3 = __half22float2(*(const __half2*)&rawa.w);
    float dacc = 0.0f;
    #pragma unroll 2
    for (int pb = p0; pb < p1; pb += 4) {
        int p = pb + g;
        bool valid = p < p1;
        int pc = valid ? p : (p1 - 1);             // clamp: always a real edge
        int t = t_sorted[pc];
        float4 raw = ((const float4*)(ttan + (size_t)t * DD))[il];   // 8 halves
        float2 b0 = __half22float2(*(const __half2*)&raw.x);
        float2 b1 = __half22float2(*(const __half2*)&raw.y);
        float2 b2 = __half22float2(*(const __half2*)&raw.z);
        float2 b3 = __half22float2(*(const __half2*)&raw.w);
        float s = a0.x * b0.x + a0.y * b0.y + a1.x * b1.x + a1.y * b1.y
                + a2.x * b2.x + a2.y * b2.y + a3.x * b3.x + a3.y * b3.y;
        s += __shfl_xor(s, 1);
        s += __shfl_xor(s, 2);                     // 4 lanes of factor f share s_f
        float m1 = fmaxf(s, __shfl_xor(s, 4));
        float mx = fmaxf(m1, __shfl_xor(m1, 8));   // max over 4 factors
        float e = __expf(s - mx);
        float sum = e;
        sum += __shfl_xor(sum, 4);
        sum += __shfl_xor(sum, 8);                 // sum over 4 factors
        float v = e * __builtin_amdgcn_rcpf(sum);  // softmaxed A for factor f
        if (valid) {
            if ((il & 3) == 0) normA[(size_t)pc * 4 + f] = v;
            dacc += v;
        }
    }
    // sum deg over the 4 edge-groups (lane position preserved)
    dacc += __shfl_xor(dacc, 16);
    dacc += __shfl_xor(dacc, 32);
    if (g == 0 && (il & 3) == 0)
        dinv1[(size_t)n * 4 + f] = 1.0f / sqrtf(fmaxf(dacc, 1e-8f));
}

// ---------------- fused iteration-1 propagation + output, batch rows only ----
// out[r] = 0.5*( ego0[n] + dinv1[n][f] * sum_p normA[p][f]*dinv1[t][f]*ego0(t) )
// 32 lanes per output row (2 rows/wave); lane j covers dims 4j..4j+3, f=j>>3.
// Pure f32 path (output precision).
__global__ void k_prop1_out(const float* __restrict__ ue, const float* __restrict__ ie,
                            const int* __restrict__ row_ptr,
                            const unsigned short* __restrict__ t_sorted,
                            const float* __restrict__ normA, const float* __restrict__ dinv1,
                            const int* __restrict__ users, const int* __restrict__ pos,
                            const int* __restrict__ neg, float* __restrict__ out) {
    int r = blockIdx.x * 8 + (threadIdx.x >> 5);
    if (r >= 3 * NB) return;
    int j = threadIdx.x & 31;
    int f = j >> 3;
    int which = r >> 12;
    int i = r & 4095;
    int n;
    if (which == 0)      n = users[i];
    else if (which == 1) n = NU + pos[i];
    else                 n = NU + neg[i];
    int p0 = row_ptr[n], p1 = row_ptr[n + 1];
    float4 acc = make_float4(0.f, 0.f, 0.f, 0.f);
    #pragma unroll 4
    for (int p = p0; p < p1; ++p) {
        int t = t_sorted[p];
        float w = normA[(size_t)p * 4 + f] * dinv1[(size_t)t * 4 + f];
        float4 v = ((const float4*)node_row(ue, ie, t))[j];
        acc.x += w * v.x; acc.y += w * v.y;
        acc.z += w * v.z; acc.w += w * v.w;
    }
    float dn = dinv1[(size_t)n * 4 + f];
    float4 e0 = ((const float4*)node_row(ue, ie, n))[j];
    ((float4*)(out + (size_t)r * DD))[j] =
        make_float4(0.5f * (e0.x + dn * acc.x), 0.5f * (e0.y + dn * acc.y),
                    0.5f * (e0.z + dn * acc.z), 0.5f * (e0.w + dn * acc.w));
}

// ---------------- launch ----------------

extern "C" void kernel_launch(void* const* d_in, const int* in_sizes, int n_in,
                              void* d_out, int out_size, void* d_ws, size_t ws_size,
                              hipStream_t stream) {
    const float* ue   = (const float*)d_in[0];
    const float* ie   = (const float*)d_in[1];
    const int* row    = (const int*)d_in[2];
    const int* col    = (const int*)d_in[3];
    const int* users  = (const int*)d_in[4];
    const int* pos    = (const int*)d_in[5];
    const int* neg    = (const int*)d_in[6];
    float* out        = (float*)d_out;

    // workspace layout (256B-aligned); total ~78 MB
    char* ws = (char*)d_ws;
    size_t off = 0;
    auto take = [&](size_t bytes) { void* p = ws + off; off += (bytes + 255) & ~(size_t)255; return p; };
    __half* fnorm    = (__half*)take((size_t)NN * DD * 2);   // 15.36 MB (fp16)
    __half* ttan     = (__half*)take((size_t)NN * DD * 2);   // 15.36 MB (fp16)
    __half* ego16    = (__half*)take((size_t)NN * DD * 2);   // 15.36 MB (fp16)
    float*  normA    = (float*)take((size_t)NE * 4 * 4);     // 19.2 MB
    float*  dinv1    = (float*)take((size_t)NN * 4 * 4);     // 0.96 MB
    float*  dinv0    = (float*)take((size_t)NN * 4);         // 0.24 MB
    int*    row_ptr  = (int*)take((size_t)(NN + 1) * 4);
    int*    counts   = (int*)take((size_t)NN * CPAD * 4);    // 3.84 MB (padded)
    int*    pre      = (int*)take((size_t)NN * 4);
    int*    bsum     = (int*)take((size_t)NBLK * 4);
    int*    boff     = (int*)take((size_t)NBLK * 4);
    int*    rank     = (int*)take((size_t)NE * 4);           // 4.8 MB
    unsigned short* t_sorted = (unsigned short*)take((size_t)NE * 2);  // 2.4 MB
    if (off > ws_size) return;  // workspace too small -> validation flags loudly

    // CSR build (padded counters, rank-split fill; fp16 copy interleaved)
    k_zero <<<(NN * CPAD + 255) / 256, 256, 0, stream>>>(counts);
    k_count<<<(NE / 4 + 255) / 256, 256, 0, stream>>>(row, col, counts, rank);
    k_tohalf<<<((NU * DD / 8) + 255) / 256, 256, 0, stream>>>(ue, ego16, NU * DD / 8);
    k_tohalf<<<((NI * DD / 8) + 255) / 256, 256, 0, stream>>>(ie, ego16 + (size_t)NU * DD, NI * DD / 8);
    k_scanA<<<NBLK, 256, 0, stream>>>(counts, pre, bsum);
    k_scanB<<<1, 256, 0, stream>>>(bsum, boff);
    k_scanC<<<NBLK, 256, 0, stream>>>(pre, boff, counts, row_ptr, dinv0);
    k_fill <<<(NE / 4 + 255) / 256, 256, 0, stream>>>(row, col, row_ptr, rank, t_sorted);
    // iteration 0 propagation (fp16 gather) + fused l2norm + tanh precompute
    k_prop0_norm<<<(NN + 7) / 8, 256, 0, stream>>>(ue, ie, ego16, row_ptr, t_sorted,
                                                   dinv0, fnorm, ttan);
    // fused attention + softmax + deg1 (4 edges in flight per wave, fp16 gather)
    k_attn_deg<<<(NN + 3) / 4, 256, 0, stream>>>(row_ptr, t_sorted, fnorm, ttan,
                                                 normA, (float*)dinv1);
    // fused iteration-1 propagation + mean + gather, batch rows only (f32 path)
    k_prop1_out<<<(3 * NB) / 8, 256, 0, stream>>>(ue, ie, row_ptr, t_sorted,
                                                  normA, (const float*)dinv1,
                                                  users, pos, neg, out);
}

// Round 10
// 285.953 us; speedup vs baseline: 1.9998x; 1.0136x over previous
//
#include <hip/hip_runtime.h>
#include <hip/hip_fp16.h>
#include <math.h>

// Problem constants (fixed by setup_inputs / reference)
#define NU 40000          // n_users
#define NI 20000          // n_items
#define NN 60000          // n_nodes
#define DD 128            // embedding dim
#define NF 4              // factors
#define ME 600000         // M (undirected interactions)
#define NE 1200000        // E = 2*M directed edges
#define NB 4096           // batch
#define NBLK 235          // ceil(NN/256) for the scan
#define CPAD 16           // counter padding: one counter per 64B line

// h/t for edge e:
//  e <  ME : h = row[e],         t = NU + col[e]
//  e >= ME : h = NU + col[e-ME], t = row[e-ME]
// Graph is symmetric: every node appearing as t also appears as h -> counts[t]>=1.

__device__ __forceinline__ const float* node_row(const float* ue, const float* ie, int n) {
    return (n < NU) ? (ue + (size_t)n * DD) : (ie + (size_t)(n - NU) * DD);
}

// f32 += dot(half2, half2) -- v_dot2_f32_f16 when available (f32 accumulate).
typedef _Float16 hf2_t __attribute__((ext_vector_type(2)));
__device__ __forceinline__ float fdot2f(unsigned int a, unsigned int b, float c) {
#if __has_builtin(__builtin_amdgcn_fdot2)
    return __builtin_amdgcn_fdot2(__builtin_bit_cast(hf2_t, a),
                                  __builtin_bit_cast(hf2_t, b), c, false);
#else
    float2 fa = __half22float2(__builtin_bit_cast(__half2, a));
    float2 fb = __half22float2(__builtin_bit_cast(__half2, b));
    return c + fa.x * fb.x + fa.y * fb.y;
#endif
}

// ---------------- CSR build ----------------

__global__ void k_zero(int* counts, unsigned char* flags) {
    int i = blockIdx.x * blockDim.x + threadIdx.x;
    if (i < NN * CPAD) counts[i] = 0;
    if (i < NN) flags[i] = 0;
}

// mark batch nodes (their normA rows are the only ones prop1 reads)
__global__ void k_flag(const int* __restrict__ users, const int* __restrict__ pos,
                       const int* __restrict__ neg, unsigned char* __restrict__ flags) {
    int i = blockIdx.x * blockDim.x + threadIdx.x;
    if (i >= 3 * NB) return;
    int which = i >> 12, k = i & 4095;
    int n = (which == 0) ? users[k] : ((which == 1) ? NU + pos[k] : NU + neg[k]);
    flags[n] = 1;
}

// count + rank assignment (4 edges/thread, int4 loads, padded counters).
// ME % 4 == 0, so a 4-edge block never straddles the h/t formula switch.
__global__ void k_count(const int* __restrict__ row, const int* __restrict__ col,
                        int* __restrict__ counts, int* __restrict__ rank) {
    int base = (blockIdx.x * blockDim.x + threadIdx.x) * 4;
    if (base >= NE) return;
    int4 h4;
    if (base < ME) {
        h4 = *(const int4*)(row + base);
    } else {
        int4 c4 = *(const int4*)(col + (base - ME));
        h4 = make_int4(NU + c4.x, NU + c4.y, NU + c4.z, NU + c4.w);
    }
    int4 r;
    r.x = atomicAdd(&counts[h4.x * CPAD], 1);
    r.y = atomicAdd(&counts[h4.y * CPAD], 1);
    r.z = atomicAdd(&counts[h4.z * CPAD], 1);
    r.w = atomicAdd(&counts[h4.w * CPAD], 1);
    *(int4*)(rank + base) = r;
}

// ---- hierarchical exclusive scan: A (per-block), B (block sums), C (apply) ----

__global__ void k_scanA(const int* __restrict__ counts, int* __restrict__ pre,
                        int* __restrict__ bsum) {
    int tid = threadIdx.x;
    int i = blockIdx.x * 256 + tid;
    int v = (i < NN) ? counts[i * CPAD] : 0;
    int lane = tid & 63, w = tid >> 6;
    int s = v;
    #pragma unroll
    for (int off = 1; off < 64; off <<= 1) {
        int o = __shfl_up(s, off);
        if (lane >= off) s += o;
    }
    __shared__ int wsum[4];
    if (lane == 63) wsum[w] = s;
    __syncthreads();
    int add = 0;
    #pragma unroll
    for (int k = 0; k < 4; ++k) add += (k < w) ? wsum[k] : 0;
    if (i < NN) pre[i] = s - v + add;              // block-local exclusive
    if (tid == 255) bsum[blockIdx.x] = add + s;    // block total
}

__global__ void k_scanB(const int* __restrict__ bsum, int* __restrict__ boff) {
    int tid = threadIdx.x;                          // one block of 256
    int v = (tid < NBLK) ? bsum[tid] : 0;
    int lane = tid & 63, w = tid >> 6;
    int s = v;
    #pragma unroll
    for (int off = 1; off < 64; off <<= 1) {
        int o = __shfl_up(s, off);
        if (lane >= off) s += o;
    }
    __shared__ int wsum[4];
    if (lane == 63) wsum[w] = s;
    __syncthreads();
    int add = 0;
    #pragma unroll
    for (int k = 0; k < 4; ++k) add += (k < w) ? wsum[k] : 0;
    if (tid < NBLK) boff[tid] = s - v + add;
}

// apply block offsets; also emit dinv0 table (deg0 = 0.25*degree)
__global__ void k_scanC(const int* __restrict__ pre, const int* __restrict__ boff,
                        const int* __restrict__ counts,
                        int* __restrict__ row_ptr, float* __restrict__ dinv0) {
    int i = blockIdx.x * 256 + threadIdx.x;
    if (i < NN) {
        row_ptr[i] = pre[i] + boff[blockIdx.x];
        dinv0[i]   = 1.0f / sqrtf(fmaxf(0.25f * (float)counts[i * CPAD], 1e-8f));
    }
    if (i == 0) row_ptr[NN] = NE;
}

// Fill CSR adjacency: ATOMIC-FREE. p = row_ptr[h] + rank[e]; uint16 payload.
__global__ void k_fill(const int* __restrict__ row, const int* __restrict__ col,
                       const int* __restrict__ row_ptr, const int* __restrict__ rank,
                       unsigned short* __restrict__ t_sorted) {
    int base = (blockIdx.x * blockDim.x + threadIdx.x) * 4;
    if (base >= NE) return;
    int4 h4, t4;
    if (base < ME) {
        h4 = *(const int4*)(row + base);
        int4 c4 = *(const int4*)(col + base);
        t4 = make_int4(NU + c4.x, NU + c4.y, NU + c4.z, NU + c4.w);
    } else {
        int4 c4 = *(const int4*)(col + (base - ME));
        h4 = make_int4(NU + c4.x, NU + c4.y, NU + c4.z, NU + c4.w);
        t4 = *(const int4*)(row + (base - ME));
    }
    int4 r = *(const int4*)(rank + base);
    t_sorted[row_ptr[h4.x] + r.x] = (unsigned short)t4.x;
    t_sorted[row_ptr[h4.y] + r.y] = (unsigned short)t4.y;
    t_sorted[row_ptr[h4.z] + r.z] = (unsigned short)t4.z;
    t_sorted[row_ptr[h4.w] + r.w] = (unsigned short)t4.w;
}

// ---------------- fp16 pre-scaled embedding table: ego16s[n] = dinv0[n]*ego[n] --
// prop0's gather then needs NO per-edge weight load or multiply.
// (dinv0<=2 for any node with an edge; products fit fp16 trivially.)
__global__ void k_prep(const float* __restrict__ ue, const float* __restrict__ ie,
                       const float* __restrict__ dinv0, __half* __restrict__ dst) {
    int i = blockIdx.x * blockDim.x + threadIdx.x;   // 8-elem group, NN*DD/8 total
    if (i >= NN * DD / 8) return;
    int n = i >> 4;                                   // 16 groups per row
    int off = (i & 15) * 8;
    const float* src = node_row(ue, ie, n) + off;
    float w = dinv0[n];
    float4 a = *(const float4*)src;
    float4 b = *(const float4*)(src + 4);
    __half2 h[4] = { __floats2half2_rn(w * a.x, w * a.y), __floats2half2_rn(w * a.z, w * a.w),
                     __floats2half2_rn(w * b.x, w * b.y), __floats2half2_rn(w * b.z, w * b.w) };
    ((float4*)dst)[i] = *(float4*)h;   // 8 halves = 16 B
}

// ---------------- iteration 0 propagation + fused l2norm + tanh precompute ----
// 32 lanes per node (2 nodes/wave, 8 nodes/block). Lane j covers dims 4j..4j+3.
// Gathers pre-scaled ego16s: inner loop = load + cvt + add only.
// fnorm[n] = l2norm_per_factor( sum_p ego16s(t_p) ), stored fp16.
// ttan[n]  = tanh(l2norm_per_factor(ego[n])), stored fp16.
__global__ void k_prop0_norm(const float* __restrict__ ue, const float* __restrict__ ie,
                             const __half* __restrict__ ego16s,
                             const int* __restrict__ row_ptr,
                             const unsigned short* __restrict__ t_sorted,
                             __half* __restrict__ fnorm, __half* __restrict__ ttan) {
    int n = blockIdx.x * 8 + (threadIdx.x >> 5);
    if (n >= NN) return;
    int j = threadIdx.x & 31;
    int p0 = row_ptr[n], p1 = row_ptr[n + 1];
    float4 acc = make_float4(0.f, 0.f, 0.f, 0.f);
    #pragma unroll 8
    for (int p = p0; p < p1; ++p) {
        int t = t_sorted[p];
        float2 raw = ((const float2*)(ego16s + (size_t)t * DD))[j];   // 4 halves
        float2 v01 = __half22float2(*(const __half2*)&raw.x);
        float2 v23 = __half22float2(*(const __half2*)&raw.y);
        acc.x += v01.x; acc.y += v01.y;
        acc.z += v23.x; acc.w += v23.y;
    }
    float ss = acc.x * acc.x + acc.y * acc.y + acc.z * acc.z + acc.w * acc.w;
    ss += __shfl_xor(ss, 1); ss += __shfl_xor(ss, 2); ss += __shfl_xor(ss, 4);
    float inv = 1.0f / fmaxf(sqrtf(ss), 1e-12f);
    __half2 f01 = __floats2half2_rn(acc.x * inv, acc.y * inv);
    __half2 f23 = __floats2half2_rn(acc.z * inv, acc.w * inv);
    __half2 fpair[2] = { f01, f23 };
    ((float2*)(fnorm + (size_t)n * DD))[j] = *(float2*)fpair;        // 4 halves

    float4 u = ((const float4*)node_row(ue, ie, n))[j];
    float s2 = u.x * u.x + u.y * u.y + u.z * u.z + u.w * u.w;
    s2 += __shfl_xor(s2, 1); s2 += __shfl_xor(s2, 2); s2 += __shfl_xor(s2, 4);
    float inv2 = 1.0f / fmaxf(sqrtf(s2), 1e-12f);
    __half2 t01 = __floats2half2_rn(tanhf(u.x * inv2), tanhf(u.y * inv2));
    __half2 t23 = __floats2half2_rn(tanhf(u.z * inv2), tanhf(u.w * inv2));
    __half2 tpair[2] = { t01, t23 };
    ((float2*)(ttan + (size_t)n * DD))[j] = *(float2*)tpair;         // 4 halves
}

// ---------------- fused attention + softmax + deg1, per node ----------------
// One wave per node; 16 lanes per edge -> 4 edges in flight, unroll 4 (16 chains).
// il = lane&15 covers dims 8*il..8*il+7, factor f = il>>2. Dot via v_dot2_f32_f16.
// normA stored ONLY for batch nodes (flags) -- prop1 reads nothing else.
__global__ void k_attn_deg(const int* __restrict__ row_ptr,
                           const unsigned short* __restrict__ t_sorted,
                           const __half* __restrict__ fnorm, const __half* __restrict__ ttan,
                           const unsigned char* __restrict__ flags,
                           float* __restrict__ normA, float* __restrict__ dinv1) {
    int n = blockIdx.x * 4 + (threadIdx.x >> 6);
    if (n >= NN) return;
    int lane = threadIdx.x & 63;
    int g  = lane >> 4;        // edge group 0..3
    int il = lane & 15;        // lane within edge
    int f  = il >> 2;          // this lane's factor
    int p0 = row_ptr[n], p1 = row_ptr[n + 1];
    bool writeA = flags[n] != 0;
    uint4 au = ((const uint4*)(fnorm + (size_t)n * DD))[il];         // 8 halves
    float dacc = 0.0f;
    #pragma unroll 4
    for (int pb = p0; pb < p1; pb += 4) {
        int p = pb + g;
        bool valid = p < p1;
        int pc = valid ? p : (p1 - 1);             // clamp: always a real edge
        int t = t_sorted[pc];
        uint4 bu = ((const uint4*)(ttan + (size_t)t * DD))[il];      // 8 halves
        float s = 0.0f;
        s = fdot2f(au.x, bu.x, s);
        s = fdot2f(au.y, bu.y, s);
        s = fdot2f(au.z, bu.z, s);
        s = fdot2f(au.w, bu.w, s);
        s += __shfl_xor(s, 1);
        s += __shfl_xor(s, 2);                     // 4 lanes of factor f share s_f
        float m1 = fmaxf(s, __shfl_xor(s, 4));
        float mx = fmaxf(m1, __shfl_xor(m1, 8));   // max over 4 factors
        float e = __expf(s - mx);
        float sum = e;
        sum += __shfl_xor(sum, 4);
        sum += __shfl_xor(sum, 8);                 // sum over 4 factors
        float v = e * __builtin_amdgcn_rcpf(sum);  // softmaxed A for factor f
        if (valid) {
            if (writeA && (il & 3) == 0) normA[(size_t)pc * 4 + f] = v;
            dacc += v;
        }
    }
    // sum deg over the 4 edge-groups (lane position preserved)
    dacc += __shfl_xor(dacc, 16);
    dacc += __shfl_xor(dacc, 32);
    if (g == 0 && (il & 3) == 0)
        dinv1[(size_t)n * 4 + f] = 1.0f / sqrtf(fmaxf(dacc, 1e-8f));
}

// ---------------- fused iteration-1 propagation + output, batch rows only ----
// out[r] = 0.5*( ego0[n] + dinv1[n][f] * sum_p normA[p][f]*dinv1[t][f]*ego0(t) )
// 32 lanes per output row (2 rows/wave); lane j covers dims 4j..4j+3, f=j>>3.
// Pure f32 path (output precision).
__global__ void k_prop1_out(const float* __restrict__ ue, const float* __restrict__ ie,
                            const int* __restrict__ row_ptr,
                            const unsigned short* __restrict__ t_sorted,
                            const float* __restrict__ normA, const float* __restrict__ dinv1,
                            const int* __restrict__ users, const int* __restrict__ pos,
                            const int* __restrict__ neg, float* __restrict__ out) {
    int r = blockIdx.x * 8 + (threadIdx.x >> 5);
    if (r >= 3 * NB) return;
    int j = threadIdx.x & 31;
    int f = j >> 3;
    int which = r >> 12;
    int i = r & 4095;
    int n;
    if (which == 0)      n = users[i];
    else if (which == 1) n = NU + pos[i];
    else                 n = NU + neg[i];
    int p0 = row_ptr[n], p1 = row_ptr[n + 1];
    float4 acc = make_float4(0.f, 0.f, 0.f, 0.f);
    #pragma unroll 4
    for (int p = p0; p < p1; ++p) {
        int t = t_sorted[p];
        float w = normA[(size_t)p * 4 + f] * dinv1[(size_t)t * 4 + f];
        float4 v = ((const float4*)node_row(ue, ie, t))[j];
        acc.x += w * v.x; acc.y += w * v.y;
        acc.z += w * v.z; acc.w += w * v.w;
    }
    float dn = dinv1[(size_t)n * 4 + f];
    float4 e0 = ((const float4*)node_row(ue, ie, n))[j];
    ((float4*)(out + (size_t)r * DD))[j] =
        make_float4(0.5f * (e0.x + dn * acc.x), 0.5f * (e0.y + dn * acc.y),
                    0.5f * (e0.z + dn * acc.z), 0.5f * (e0.w + dn * acc.w));
}

// ---------------- launch ----------------

extern "C" void kernel_launch(void* const* d_in, const int* in_sizes, int n_in,
                              void* d_out, int out_size, void* d_ws, size_t ws_size,
                              hipStream_t stream) {
    const float* ue   = (const float*)d_in[0];
    const float* ie   = (const float*)d_in[1];
    const int* row    = (const int*)d_in[2];
    const int* col    = (const int*)d_in[3];
    const int* users  = (const int*)d_in[4];
    const int* pos    = (const int*)d_in[5];
    const int* neg    = (const int*)d_in[6];
    float* out        = (float*)d_out;

    // workspace layout (256B-aligned); total ~78 MB
    char* ws = (char*)d_ws;
    size_t off = 0;
    auto take = [&](size_t bytes) { void* p = ws + off; off += (bytes + 255) & ~(size_t)255; return p; };
    __half* fnorm    = (__half*)take((size_t)NN * DD * 2);   // 15.36 MB (fp16)
    __half* ttan     = (__half*)take((size_t)NN * DD * 2);   // 15.36 MB (fp16)
    __half* ego16s   = (__half*)take((size_t)NN * DD * 2);   // 15.36 MB (fp16, pre-scaled)
    float*  normA    = (float*)take((size_t)NE * 4 * 4);     // 19.2 MB
    float*  dinv1    = (float*)take((size_t)NN * 4 * 4);     // 0.96 MB
    float*  dinv0    = (float*)take((size_t)NN * 4);         // 0.24 MB
    int*    row_ptr  = (int*)take((size_t)(NN + 1) * 4);
    int*    counts   = (int*)take((size_t)NN * CPAD * 4);    // 3.84 MB (padded)
    int*    pre      = (int*)take((size_t)NN * 4);
    int*    bsum     = (int*)take((size_t)NBLK * 4);
    int*    boff     = (int*)take((size_t)NBLK * 4);
    int*    rank     = (int*)take((size_t)NE * 4);           // 4.8 MB
    unsigned short* t_sorted = (unsigned short*)take((size_t)NE * 2);  // 2.4 MB
    unsigned char*  flags    = (unsigned char*)take((size_t)NN);       // 60 KB
    if (off > ws_size) return;  // workspace too small -> validation flags loudly

    // CSR build (padded counters, rank-split fill)
    k_zero <<<(NN * CPAD + 255) / 256, 256, 0, stream>>>(counts, flags);
    k_flag <<<(3 * NB + 255) / 256, 256, 0, stream>>>(users, pos, neg, flags);
    k_count<<<(NE / 4 + 255) / 256, 256, 0, stream>>>(row, col, counts, rank);
    k_scanA<<<NBLK, 256, 0, stream>>>(counts, pre, bsum);
    k_scanB<<<1, 256, 0, stream>>>(bsum, boff);
    k_scanC<<<NBLK, 256, 0, stream>>>(pre, boff, counts, row_ptr, dinv0);
    // pre-scaled fp16 table (needs dinv0)
    k_prep <<<(NN * DD / 8 + 255) / 256, 256, 0, stream>>>(ue, ie, dinv0, ego16s);
    k_fill <<<(NE / 4 + 255) / 256, 256, 0, stream>>>(row, col, row_ptr, rank, t_sorted);
    // iteration 0 propagation (pre-scaled fp16 gather) + l2norm + tanh
    k_prop0_norm<<<(NN + 7) / 8, 256, 0, stream>>>(ue, ie, ego16s, row_ptr, t_sorted,
                                                   fnorm, ttan);
    // fused attention + softmax + deg1 (fdot2, unroll 4, flag-gated normA store)
    k_attn_deg<<<(NN + 3) / 4, 256, 0, stream>>>(row_ptr, t_sorted, fnorm, ttan,
                                                 flags, normA, (float*)dinv1);
    // fused iteration-1 propagation + mean + gather, batch rows only (f32 path)
    k_prop1_out<<<(3 * NB) / 8, 256, 0, stream>>>(ue, ie, row_ptr, t_sorted,
                                                  normA, (const float*)dinv1,
                                                  users, pos, neg, out);
}

// Round 11
// 277.350 us; speedup vs baseline: 2.0619x; 1.0310x over previous
//
#include <hip/hip_runtime.h>
#include <hip/hip_fp16.h>
#include <math.h>

// Problem constants (fixed by setup_inputs / reference)
#define NU 40000          // n_users
#define NI 20000          // n_items
#define NN 60000          // n_nodes
#define DD 128            // embedding dim
#define NF 4              // factors
#define ME 600000         // M (undirected interactions)
#define NE 1200000        // E = 2*M directed edges
#define NB 4096           // batch
#define NBLK 235          // ceil(NN/256) for the scan
#define CPAD 16           // counter padding: one counter per 64B line

// h/t for edge e:
//  e <  ME : h = row[e],         t = NU + col[e]
//  e >= ME : h = NU + col[e-ME], t = row[e-ME]

__device__ __forceinline__ const float* node_row(const float* ue, const float* ie, int n) {
    return (n < NU) ? (ue + (size_t)n * DD) : (ie + (size_t)(n - NU) * DD);
}

// f32 += dot(half2, half2) -- v_dot2_f32_f16 when available (f32 accumulate).
typedef _Float16 hf2_t __attribute__((ext_vector_type(2)));
__device__ __forceinline__ float fdot2f(unsigned int a, unsigned int b, float c) {
#if __has_builtin(__builtin_amdgcn_fdot2)
    return __builtin_amdgcn_fdot2(__builtin_bit_cast(hf2_t, a),
                                  __builtin_bit_cast(hf2_t, b), c, false);
#else
    float2 fa = __half22float2(__builtin_bit_cast(__half2, a));
    float2 fb = __half22float2(__builtin_bit_cast(__half2, b));
    return c + fa.x * fb.x + fa.y * fb.y;
#endif
}

// ---------------- CSR build ----------------

__global__ void k_zero(int* counts, unsigned char* flags) {
    int i = blockIdx.x * blockDim.x + threadIdx.x;
    if (i < NN * CPAD) counts[i] = 0;
    if (i < NN) flags[i] = 0;
}

// mark batch nodes (their normA rows are the only ones prop1 reads)
__global__ void k_flag(const int* __restrict__ users, const int* __restrict__ pos,
                       const int* __restrict__ neg, unsigned char* __restrict__ flags) {
    int i = blockIdx.x * blockDim.x + threadIdx.x;
    if (i >= 3 * NB) return;
    int which = i >> 12, k = i & 4095;
    int n = (which == 0) ? users[k] : ((which == 1) ? NU + pos[k] : NU + neg[k]);
    flags[n] = 1;
}

// count + rank assignment (4 edges/thread, int4 loads, padded counters).
// ME % 4 == 0, so a 4-edge block never straddles the h/t formula switch.
__global__ void k_count(const int* __restrict__ row, const int* __restrict__ col,
                        int* __restrict__ counts, int* __restrict__ rank) {
    int base = (blockIdx.x * blockDim.x + threadIdx.x) * 4;
    if (base >= NE) return;
    int4 h4;
    if (base < ME) {
        h4 = *(const int4*)(row + base);
    } else {
        int4 c4 = *(const int4*)(col + (base - ME));
        h4 = make_int4(NU + c4.x, NU + c4.y, NU + c4.z, NU + c4.w);
    }
    int4 r;
    r.x = atomicAdd(&counts[h4.x * CPAD], 1);
    r.y = atomicAdd(&counts[h4.y * CPAD], 1);
    r.z = atomicAdd(&counts[h4.z * CPAD], 1);
    r.w = atomicAdd(&counts[h4.w * CPAD], 1);
    *(int4*)(rank + base) = r;
}

// ---- hierarchical exclusive scan: A (per-block), B (block sums), C (apply) ----

__global__ void k_scanA(const int* __restrict__ counts, int* __restrict__ pre,
                        int* __restrict__ bsum) {
    int tid = threadIdx.x;
    int i = blockIdx.x * 256 + tid;
    int v = (i < NN) ? counts[i * CPAD] : 0;
    int lane = tid & 63, w = tid >> 6;
    int s = v;
    #pragma unroll
    for (int off = 1; off < 64; off <<= 1) {
        int o = __shfl_up(s, off);
        if (lane >= off) s += o;
    }
    __shared__ int wsum[4];
    if (lane == 63) wsum[w] = s;
    __syncthreads();
    int add = 0;
    #pragma unroll
    for (int k = 0; k < 4; ++k) add += (k < w) ? wsum[k] : 0;
    if (i < NN) pre[i] = s - v + add;              // block-local exclusive
    if (tid == 255) bsum[blockIdx.x] = add + s;    // block total
}

__global__ void k_scanB(const int* __restrict__ bsum, int* __restrict__ boff) {
    int tid = threadIdx.x;                          // one block of 256
    int v = (tid < NBLK) ? bsum[tid] : 0;
    int lane = tid & 63, w = tid >> 6;
    int s = v;
    #pragma unroll
    for (int off = 1; off < 64; off <<= 1) {
        int o = __shfl_up(s, off);
        if (lane >= off) s += o;
    }
    __shared__ int wsum[4];
    if (lane == 63) wsum[w] = s;
    __syncthreads();
    int add = 0;
    #pragma unroll
    for (int k = 0; k < 4; ++k) add += (k < w) ? wsum[k] : 0;
    if (tid < NBLK) boff[tid] = s - v + add;
}

// apply block offsets; also emit dinv0 table (deg0 = 0.25*degree)
__global__ void k_scanC(const int* __restrict__ pre, const int* __restrict__ boff,
                        const int* __restrict__ counts,
                        int* __restrict__ row_ptr, float* __restrict__ dinv0) {
    int i = blockIdx.x * 256 + threadIdx.x;
    if (i < NN) {
        row_ptr[i] = pre[i] + boff[blockIdx.x];
        dinv0[i]   = 1.0f / sqrtf(fmaxf(0.25f * (float)counts[i * CPAD], 1e-8f));
    }
    if (i == 0) row_ptr[NN] = NE;
}

// Fill CSR adjacency: ATOMIC-FREE. p = row_ptr[h] + rank[e]; uint16 payload.
__global__ void k_fill(const int* __restrict__ row, const int* __restrict__ col,
                       const int* __restrict__ row_ptr, const int* __restrict__ rank,
                       unsigned short* __restrict__ t_sorted) {
    int base = (blockIdx.x * blockDim.x + threadIdx.x) * 4;
    if (base >= NE) return;
    int4 h4, t4;
    if (base < ME) {
        h4 = *(const int4*)(row + base);
        int4 c4 = *(const int4*)(col + base);
        t4 = make_int4(NU + c4.x, NU + c4.y, NU + c4.z, NU + c4.w);
    } else {
        int4 c4 = *(const int4*)(col + (base - ME));
        h4 = make_int4(NU + c4.x, NU + c4.y, NU + c4.z, NU + c4.w);
        t4 = *(const int4*)(row + (base - ME));
    }
    int4 r = *(const int4*)(rank + base);
    t_sorted[row_ptr[h4.x] + r.x] = (unsigned short)t4.x;
    t_sorted[row_ptr[h4.y] + r.y] = (unsigned short)t4.y;
    t_sorted[row_ptr[h4.z] + r.z] = (unsigned short)t4.z;
    t_sorted[row_ptr[h4.w] + r.w] = (unsigned short)t4.w;
}

// ---------------- fp16 tables: ego16s = dinv0*ego, ttan = tanh(l2norm_f(ego)) --
// 16 threads per row (thread covers 8 dims = exactly the attention dot layout);
// per-factor l2norm via 2 shfl_xor within the 4-thread factor group.
__global__ void k_prep(const float* __restrict__ ue, const float* __restrict__ ie,
                       const float* __restrict__ dinv0,
                       __half* __restrict__ ego16s, __half* __restrict__ ttan) {
    int i = blockIdx.x * blockDim.x + threadIdx.x;   // NN*16 threads
    if (i >= NN * 16) return;
    int n = i >> 4;
    int il = i & 15;                                  // dims 8*il .. 8*il+7
    const float* src = node_row(ue, ie, n) + il * 8;
    float4 a = *(const float4*)src;
    float4 b = *(const float4*)(src + 4);
    // pre-scaled fp16 ego
    float w = dinv0[n];
    __half2 h[4] = { __floats2half2_rn(w * a.x, w * a.y), __floats2half2_rn(w * a.z, w * a.w),
                     __floats2half2_rn(w * b.x, w * b.y), __floats2half2_rn(w * b.z, w * b.w) };
    ((float4*)ego16s)[i] = *(float4*)h;
    // per-factor l2norm + tanh (factor = il>>2; 4 threads per factor, same wave)
    float s2 = a.x * a.x + a.y * a.y + a.z * a.z + a.w * a.w
             + b.x * b.x + b.y * b.y + b.z * b.z + b.w * b.w;
    s2 += __shfl_xor(s2, 1); s2 += __shfl_xor(s2, 2);
    float inv = 1.0f / fmaxf(sqrtf(s2), 1e-12f);
    __half2 t[4] = { __floats2half2_rn(tanhf(a.x * inv), tanhf(a.y * inv)),
                     __floats2half2_rn(tanhf(a.z * inv), tanhf(a.w * inv)),
                     __floats2half2_rn(tanhf(b.x * inv), tanhf(b.y * inv)),
                     __floats2half2_rn(tanhf(b.z * inv), tanhf(b.w * inv)) };
    ((float4*)ttan)[i] = *(float4*)t;
}

// ---------------- FUSED prop0 + attention + softmax + deg1, per node ----------
// One wave per node, fnorm never leaves registers.
// Phase A: sum ego16s[t] over CSR range (2 edges in flight, 32 lanes x 4 dims),
//          per-factor l2norm in-register, repack to 16-lane dot layout (4 shfl).
// Phase B: attention dots vs ttan[t] (4 edges x 16 lanes, fdot2), softmax,
//          flag-gated normA store, deg1 accumulate -> dinv1.
__global__ void k_mega(const int* __restrict__ row_ptr,
                       const unsigned short* __restrict__ t_sorted,
                       const __half* __restrict__ ego16s, const __half* __restrict__ ttan,
                       const unsigned char* __restrict__ flags,
                       float* __restrict__ normA, float* __restrict__ dinv1) {
    int n = blockIdx.x * 4 + (threadIdx.x >> 6);
    if (n >= NN) return;
    int lane = threadIdx.x & 63;
    int p0 = row_ptr[n], p1 = row_ptr[n + 1];
    bool writeA = flags[n] != 0;

    // ---- phase A ----
    int g2 = lane >> 5;          // edge group 0/1
    int jl = lane & 31;          // dims 4*jl .. 4*jl+3
    float4 acc = make_float4(0.f, 0.f, 0.f, 0.f);
    #pragma unroll 4
    for (int pb = p0; pb < p1; pb += 2) {
        int p = pb + g2;
        bool valid = p < p1;
        int pc = valid ? p : (p1 - 1);                 // loop runs only if p1>p0
        float m = valid ? 1.0f : 0.0f;
        int t = t_sorted[pc];
        float2 raw = ((const float2*)(ego16s + (size_t)t * DD))[jl];  // 4 halves
        float2 v01 = __half22float2(*(const __half2*)&raw.x);
        float2 v23 = __half22float2(*(const __half2*)&raw.y);
        acc.x += m * v01.x; acc.y += m * v01.y;
        acc.z += m * v23.x; acc.w += m * v23.y;
    }
    // combine the two edge groups (dim positions aligned across wave halves)
    acc.x += __shfl_xor(acc.x, 32); acc.y += __shfl_xor(acc.y, 32);
    acc.z += __shfl_xor(acc.z, 32); acc.w += __shfl_xor(acc.w, 32);
    // per-factor l2norm: factor = jl>>3 (8 lanes per factor)
    float ss = acc.x * acc.x + acc.y * acc.y + acc.z * acc.z + acc.w * acc.w;
    ss += __shfl_xor(ss, 1); ss += __shfl_xor(ss, 2); ss += __shfl_xor(ss, 4);
    float inv = 1.0f / fmaxf(sqrtf(ss), 1e-12f);
    // pack normalized dims to fp16 pairs (same rounding as the old fnorm store)
    unsigned int u01 = __builtin_bit_cast(unsigned int,
                         __floats2half2_rn(acc.x * inv, acc.y * inv));
    unsigned int u23 = __builtin_bit_cast(unsigned int,
                         __floats2half2_rn(acc.z * inv, acc.w * inv));
    // redistribute to phase-B layout: lane (il) needs dims 8*il..8*il+7
    int il = lane & 15;
    uint4 au;
    au.x = __shfl(u01, 2 * il);        // dims 8il .. 8il+1
    au.y = __shfl(u23, 2 * il);        // dims 8il+2 .. 8il+3
    au.z = __shfl(u01, 2 * il + 1);    // dims 8il+4 .. 8il+5
    au.w = __shfl(u23, 2 * il + 1);    // dims 8il+6 .. 8il+7

    // ---- phase B ----
    int g = lane >> 4;         // edge group 0..3
    int f = il >> 2;           // this lane's factor
    float dacc = 0.0f;
    #pragma unroll 4
    for (int pb = p0; pb < p1; pb += 4) {
        int p = pb + g;
        bool valid = p < p1;
        int pc = valid ? p : (p1 - 1);
        int t = t_sorted[pc];
        uint4 bu = ((const uint4*)(ttan + (size_t)t * DD))[il];      // 8 halves
        float s = 0.0f;
        s = fdot2f(au.x, bu.x, s);
        s = fdot2f(au.y, bu.y, s);
        s = fdot2f(au.z, bu.z, s);
        s = fdot2f(au.w, bu.w, s);
        s += __shfl_xor(s, 1);
        s += __shfl_xor(s, 2);                     // 4 lanes of factor f share s_f
        float m1 = fmaxf(s, __shfl_xor(s, 4));
        float mx = fmaxf(m1, __shfl_xor(m1, 8));   // max over 4 factors
        float e = __expf(s - mx);
        float sum = e;
        sum += __shfl_xor(sum, 4);
        sum += __shfl_xor(sum, 8);                 // sum over 4 factors
        float v = e * __builtin_amdgcn_rcpf(sum);  // softmaxed A for factor f
        if (valid) {
            if (writeA && (il & 3) == 0) normA[(size_t)pc * 4 + f] = v;
            dacc += v;
        }
    }
    // sum deg over the 4 edge-groups (lane position preserved)
    dacc += __shfl_xor(dacc, 16);
    dacc += __shfl_xor(dacc, 32);
    if (g == 0 && (il & 3) == 0)
        dinv1[(size_t)n * 4 + f] = 1.0f / sqrtf(fmaxf(dacc, 1e-8f));
}

// ---------------- fused iteration-1 propagation + output, batch rows only ----
// out[r] = 0.5*( ego0[n] + dinv1[n][f] * sum_p normA[p][f]*dinv1[t][f]*ego0(t) )
// 32 lanes per output row (2 rows/wave); lane j covers dims 4j..4j+3, f=j>>3.
// Pure f32 path (output precision).
__global__ void k_prop1_out(const float* __restrict__ ue, const float* __restrict__ ie,
                            const int* __restrict__ row_ptr,
                            const unsigned short* __restrict__ t_sorted,
                            const float* __restrict__ normA, const float* __restrict__ dinv1,
                            const int* __restrict__ users, const int* __restrict__ pos,
                            const int* __restrict__ neg, float* __restrict__ out) {
    int r = blockIdx.x * 8 + (threadIdx.x >> 5);
    if (r >= 3 * NB) return;
    int j = threadIdx.x & 31;
    int f = j >> 3;
    int which = r >> 12;
    int i = r & 4095;
    int n;
    if (which == 0)      n = users[i];
    else if (which == 1) n = NU + pos[i];
    else                 n = NU + neg[i];
    int p0 = row_ptr[n], p1 = row_ptr[n + 1];
    float4 acc = make_float4(0.f, 0.f, 0.f, 0.f);
    #pragma unroll 4
    for (int p = p0; p < p1; ++p) {
        int t = t_sorted[p];
        float w = normA[(size_t)p * 4 + f] * dinv1[(size_t)t * 4 + f];
        float4 v = ((const float4*)node_row(ue, ie, t))[j];
        acc.x += w * v.x; acc.y += w * v.y;
        acc.z += w * v.z; acc.w += w * v.w;
    }
    float dn = dinv1[(size_t)n * 4 + f];
    float4 e0 = ((const float4*)node_row(ue, ie, n))[j];
    ((float4*)(out + (size_t)r * DD))[j] =
        make_float4(0.5f * (e0.x + dn * acc.x), 0.5f * (e0.y + dn * acc.y),
                    0.5f * (e0.z + dn * acc.z), 0.5f * (e0.w + dn * acc.w));
}

// ---------------- launch ----------------

extern "C" void kernel_launch(void* const* d_in, const int* in_sizes, int n_in,
                              void* d_out, int out_size, void* d_ws, size_t ws_size,
                              hipStream_t stream) {
    const float* ue   = (const float*)d_in[0];
    const float* ie   = (const float*)d_in[1];
    const int* row    = (const int*)d_in[2];
    const int* col    = (const int*)d_in[3];
    const int* users  = (const int*)d_in[4];
    const int* pos    = (const int*)d_in[5];
    const int* neg    = (const int*)d_in[6];
    float* out        = (float*)d_out;

    // workspace layout (256B-aligned); total ~62 MB
    char* ws = (char*)d_ws;
    size_t off = 0;
    auto take = [&](size_t bytes) { void* p = ws + off; off += (bytes + 255) & ~(size_t)255; return p; };
    __half* ttan     = (__half*)take((size_t)NN * DD * 2);   // 15.36 MB (fp16)
    __half* ego16s   = (__half*)take((size_t)NN * DD * 2);   // 15.36 MB (fp16, pre-scaled)
    float*  normA    = (float*)take((size_t)NE * 4 * 4);     // 19.2 MB
    float*  dinv1    = (float*)take((size_t)NN * 4 * 4);     // 0.96 MB
    float*  dinv0    = (float*)take((size_t)NN * 4);         // 0.24 MB
    int*    row_ptr  = (int*)take((size_t)(NN + 1) * 4);
    int*    counts   = (int*)take((size_t)NN * CPAD * 4);    // 3.84 MB (padded)
    int*    pre      = (int*)take((size_t)NN * 4);
    int*    bsum     = (int*)take((size_t)NBLK * 4);
    int*    boff     = (int*)take((size_t)NBLK * 4);
    int*    rank     = (int*)take((size_t)NE * 4);           // 4.8 MB
    unsigned short* t_sorted = (unsigned short*)take((size_t)NE * 2);  // 2.4 MB
    unsigned char*  flags    = (unsigned char*)take((size_t)NN);       // 60 KB
    if (off > ws_size) return;  // workspace too small -> validation flags loudly

    // CSR build (padded counters, rank-split fill)
    k_zero <<<(NN * CPAD + 255) / 256, 256, 0, stream>>>(counts, flags);
    k_flag <<<(3 * NB + 255) / 256, 256, 0, stream>>>(users, pos, neg, flags);
    k_count<<<(NE / 4 + 255) / 256, 256, 0, stream>>>(row, col, counts, rank);
    k_scanA<<<NBLK, 256, 0, stream>>>(counts, pre, bsum);
    k_scanB<<<1, 256, 0, stream>>>(bsum, boff);
    k_scanC<<<NBLK, 256, 0, stream>>>(pre, boff, counts, row_ptr, dinv0);
    // fp16 tables (pre-scaled ego + tanh(l2norm)) -- needs dinv0
    k_prep <<<(NN * 16 + 255) / 256, 256, 0, stream>>>(ue, ie, dinv0, ego16s, ttan);
    k_fill <<<(NE / 4 + 255) / 256, 256, 0, stream>>>(row, col, row_ptr, rank, t_sorted);
    // fused prop0 + attention + softmax + deg1 (fnorm stays in registers)
    k_mega <<<(NN + 3) / 4, 256, 0, stream>>>(row_ptr, t_sorted, ego16s, ttan,
                                              flags, normA, (float*)dinv1);
    // fused iteration-1 propagation + mean + gather, batch rows only (f32 path)
    k_prop1_out<<<(3 * NB) / 8, 256, 0, stream>>>(ue, ie, row_ptr, t_sorted,
                                                  normA, (const float*)dinv1,
                                                  users, pos, neg, out);
}

// Round 12
// 276.998 us; speedup vs baseline: 2.0645x; 1.0013x over previous
//
#include <hip/hip_runtime.h>
#include <hip/hip_fp16.h>
#include <math.h>

// Problem constants (fixed by setup_inputs / reference)
#define NU 40000          // n_users
#define NI 20000          // n_items
#define NN 60000          // n_nodes
#define DD 128            // embedding dim
#define NF 4              // factors
#define ME 600000         // M (undirected interactions)
#define NE 1200000        // E = 2*M directed edges
#define NB 4096           // batch
#define NBLK 235          // ceil(NN/256) for the scan
#define CPAD 16           // counter padding: one counter per 64B line

// Edge pairing: undirected pair i gives directed edges i (h=row,t=NU+col)
// and i+ME (h=NU+col, t=row). One thread handles both directions.

__device__ __forceinline__ const float* node_row(const float* ue, const float* ie, int n) {
    return (n < NU) ? (ue + (size_t)n * DD) : (ie + (size_t)(n - NU) * DD);
}

// f32 += dot(half2, half2) -- v_dot2_f32_f16 when available (f32 accumulate).
typedef _Float16 hf2_t __attribute__((ext_vector_type(2)));
__device__ __forceinline__ float fdot2f(unsigned int a, unsigned int b, float c) {
#if __has_builtin(__builtin_amdgcn_fdot2)
    return __builtin_amdgcn_fdot2(__builtin_bit_cast(hf2_t, a),
                                  __builtin_bit_cast(hf2_t, b), c, false);
#else
    float2 fa = __half22float2(__builtin_bit_cast(__half2, a));
    float2 fb = __half22float2(__builtin_bit_cast(__half2, b));
    return c + fa.x * fb.x + fa.y * fb.y;
#endif
}

__device__ __forceinline__ unsigned int packh2(float a, float b) {
    return __builtin_bit_cast(unsigned int, __floats2half2_rn(a, b));
}

// ---------------- CSR build ----------------

__global__ void k_zero(int* counts, unsigned char* flags) {
    int i = blockIdx.x * blockDim.x + threadIdx.x;
    if (i < NN * CPAD) counts[i] = 0;
    if (i < NN) flags[i] = 0;
}

// mark batch nodes (their normA rows are the only ones prop1 reads)
__global__ void k_flag(const int* __restrict__ users, const int* __restrict__ pos,
                       const int* __restrict__ neg, unsigned char* __restrict__ flags) {
    int i = blockIdx.x * blockDim.x + threadIdx.x;
    if (i >= 3 * NB) return;
    int which = i >> 12, k = i & 4095;
    int n = (which == 0) ? users[k] : ((which == 1) ? NU + pos[k] : NU + neg[k]);
    flags[n] = 1;
}

// count + rank: 4 undirected pairs/thread = 8 directed edges, one row/col load.
// rank stored uint16 (max degree << 64K). Padded counters (64B/line).
__global__ void k_count(const int* __restrict__ row, const int* __restrict__ col,
                        int* __restrict__ counts, unsigned short* __restrict__ rank) {
    int base = (blockIdx.x * blockDim.x + threadIdx.x) * 4;
    if (base >= ME) return;
    int4 r4 = *(const int4*)(row + base);
    int4 c4 = *(const int4*)(col + base);
    unsigned int f0 = atomicAdd(&counts[r4.x * CPAD], 1);
    unsigned int v0 = atomicAdd(&counts[(NU + c4.x) * CPAD], 1);
    unsigned int f1 = atomicAdd(&counts[r4.y * CPAD], 1);
    unsigned int v1 = atomicAdd(&counts[(NU + c4.y) * CPAD], 1);
    unsigned int f2 = atomicAdd(&counts[r4.z * CPAD], 1);
    unsigned int v2 = atomicAdd(&counts[(NU + c4.z) * CPAD], 1);
    unsigned int f3 = atomicAdd(&counts[r4.w * CPAD], 1);
    unsigned int v3 = atomicAdd(&counts[(NU + c4.w) * CPAD], 1);
    uint2 fw = make_uint2(f0 | (f1 << 16), f2 | (f3 << 16));
    uint2 rv = make_uint2(v0 | (v1 << 16), v2 | (v3 << 16));
    *(uint2*)(rank + base)      = fw;   // forward edges e = base..base+3
    *(uint2*)(rank + ME + base) = rv;   // reverse edges e+ME
}

// ---- hierarchical exclusive scan: A (per-block), B (block sums), C (apply) ----

__global__ void k_scanA(const int* __restrict__ counts, int* __restrict__ pre,
                        int* __restrict__ bsum) {
    int tid = threadIdx.x;
    int i = blockIdx.x * 256 + tid;
    int v = (i < NN) ? counts[i * CPAD] : 0;
    int lane = tid & 63, w = tid >> 6;
    int s = v;
    #pragma unroll
    for (int off = 1; off < 64; off <<= 1) {
        int o = __shfl_up(s, off);
        if (lane >= off) s += o;
    }
    __shared__ int wsum[4];
    if (lane == 63) wsum[w] = s;
    __syncthreads();
    int add = 0;
    #pragma unroll
    for (int k = 0; k < 4; ++k) add += (k < w) ? wsum[k] : 0;
    if (i < NN) pre[i] = s - v + add;              // block-local exclusive
    if (tid == 255) bsum[blockIdx.x] = add + s;    // block total
}

__global__ void k_scanB(const int* __restrict__ bsum, int* __restrict__ boff) {
    int tid = threadIdx.x;                          // one block of 256
    int v = (tid < NBLK) ? bsum[tid] : 0;
    int lane = tid & 63, w = tid >> 6;
    int s = v;
    #pragma unroll
    for (int off = 1; off < 64; off <<= 1) {
        int o = __shfl_up(s, off);
        if (lane >= off) s += o;
    }
    __shared__ int wsum[4];
    if (lane == 63) wsum[w] = s;
    __syncthreads();
    int add = 0;
    #pragma unroll
    for (int k = 0; k < 4; ++k) add += (k < w) ? wsum[k] : 0;
    if (tid < NBLK) boff[tid] = s - v + add;
}

// apply block offsets; emit dinv0 = rsqrt(max(0.25*deg,eps)) and inv0 = 1/dinv0
__global__ void k_scanC(const int* __restrict__ pre, const int* __restrict__ boff,
                        const int* __restrict__ counts, int* __restrict__ row_ptr,
                        float* __restrict__ dinv0, float* __restrict__ inv0) {
    int i = blockIdx.x * 256 + threadIdx.x;
    if (i < NN) {
        row_ptr[i] = pre[i] + boff[blockIdx.x];
        float d = sqrtf(fmaxf(0.25f * (float)counts[i * CPAD], 1e-8f));
        dinv0[i] = 1.0f / d;
        inv0[i]  = d;
    }
    if (i == 0) row_ptr[NN] = NE;
}

// Fill CSR adjacency: ATOMIC-FREE, paired (both directions per pair, one load).
__global__ void k_fill(const int* __restrict__ row, const int* __restrict__ col,
                       const int* __restrict__ row_ptr,
                       const unsigned short* __restrict__ rank,
                       unsigned short* __restrict__ t_sorted) {
    int base = (blockIdx.x * blockDim.x + threadIdx.x) * 4;
    if (base >= ME) return;
    int4 r4 = *(const int4*)(row + base);
    int4 c4 = *(const int4*)(col + base);
    uint2 fw = *(const uint2*)(rank + base);
    uint2 rv = *(const uint2*)(rank + ME + base);
    t_sorted[row_ptr[r4.x]      + (fw.x & 0xffff)] = (unsigned short)(NU + c4.x);
    t_sorted[row_ptr[r4.y]      + (fw.x >> 16)]    = (unsigned short)(NU + c4.y);
    t_sorted[row_ptr[r4.z]      + (fw.y & 0xffff)] = (unsigned short)(NU + c4.z);
    t_sorted[row_ptr[r4.w]      + (fw.y >> 16)]    = (unsigned short)(NU + c4.w);
    t_sorted[row_ptr[NU + c4.x] + (rv.x & 0xffff)] = (unsigned short)r4.x;
    t_sorted[row_ptr[NU + c4.y] + (rv.x >> 16)]    = (unsigned short)r4.y;
    t_sorted[row_ptr[NU + c4.z] + (rv.y & 0xffff)] = (unsigned short)r4.z;
    t_sorted[row_ptr[NU + c4.w] + (rv.y >> 16)]    = (unsigned short)r4.w;
}

// ---------------- fp16 tables: ego16s = dinv0*ego, ttan = tanh(l2norm_f(ego)) --
// 16 threads per row (thread covers 8 dims = exactly the attention dot layout);
// per-factor l2norm via 2 shfl_xor within the 4-thread factor group.
__global__ void k_prep(const float* __restrict__ ue, const float* __restrict__ ie,
                       const float* __restrict__ dinv0,
                       __half* __restrict__ ego16s, __half* __restrict__ ttan) {
    int i = blockIdx.x * blockDim.x + threadIdx.x;   // NN*16 threads
    if (i >= NN * 16) return;
    int n = i >> 4;
    int il = i & 15;                                  // dims 8*il .. 8*il+7
    const float* src = node_row(ue, ie, n) + il * 8;
    float4 a = *(const float4*)src;
    float4 b = *(const float4*)(src + 4);
    // pre-scaled fp16 ego
    float w = dinv0[n];
    __half2 h[4] = { __floats2half2_rn(w * a.x, w * a.y), __floats2half2_rn(w * a.z, w * a.w),
                     __floats2half2_rn(w * b.x, w * b.y), __floats2half2_rn(w * b.z, w * b.w) };
    ((float4*)ego16s)[i] = *(float4*)h;
    // per-factor l2norm + tanh (factor = il>>2; 4 threads per factor, same wave)
    float s2 = a.x * a.x + a.y * a.y + a.z * a.z + a.w * a.w
             + b.x * b.x + b.y * b.y + b.z * b.z + b.w * b.w;
    s2 += __shfl_xor(s2, 1); s2 += __shfl_xor(s2, 2);
    float inv = 1.0f / fmaxf(sqrtf(s2), 1e-12f);
    __half2 t[4] = { __floats2half2_rn(tanhf(a.x * inv), tanhf(a.y * inv)),
                     __floats2half2_rn(tanhf(a.z * inv), tanhf(a.w * inv)),
                     __floats2half2_rn(tanhf(b.x * inv), tanhf(b.y * inv)),
                     __floats2half2_rn(tanhf(b.z * inv), tanhf(b.w * inv)) };
    ((float4*)ttan)[i] = *(float4*)t;
}

// ---------------- FUSED prop0 + attention + softmax + deg1, per node ----------
// One wave per node, fnorm never leaves registers. Both phases use the SAME
// 16-lane layout (il covers dims 8*il..8*il+7, 4 edge-groups g) -> no repack.
// Phase A: sum ego16s[t] (4 edges in flight, group-uniform tail branch),
//          per-factor l2norm in-register, pack to fp16.
// Phase B: fdot2 attention, softmax, flag-gated fp16 normA store, deg1.
__global__ void k_mega(const int* __restrict__ row_ptr,
                       const unsigned short* __restrict__ t_sorted,
                       const __half* __restrict__ ego16s, const __half* __restrict__ ttan,
                       const unsigned char* __restrict__ flags,
                       __half* __restrict__ normA, float* __restrict__ dinv1) {
    int n = blockIdx.x * 4 + (threadIdx.x >> 6);
    if (n >= NN) return;
    int lane = threadIdx.x & 63;
    int g  = lane >> 4;        // edge group 0..3
    int il = lane & 15;        // dims 8*il .. 8*il+7
    int f  = il >> 2;          // this lane's factor
    int p0 = row_ptr[n], p1 = row_ptr[n + 1];
    bool writeA = flags[n] != 0;

    // ---- phase A: fe0 partial sums (f32), 4 edges in flight ----
    float4 acA = make_float4(0.f, 0.f, 0.f, 0.f);
    float4 acB = make_float4(0.f, 0.f, 0.f, 0.f);
    #pragma unroll 2
    for (int pb = p0; pb < p1; pb += 4) {
        int p = pb + g;
        if (p < p1) {                                  // group-uniform
            int t = t_sorted[p];
            uint4 raw = ((const uint4*)(ego16s + (size_t)t * DD))[il];  // 8 halves
            float2 v0 = __half22float2(__builtin_bit_cast(__half2, raw.x));
            float2 v1 = __half22float2(__builtin_bit_cast(__half2, raw.y));
            float2 v2 = __half22float2(__builtin_bit_cast(__half2, raw.z));
            float2 v3 = __half22float2(__builtin_bit_cast(__half2, raw.w));
            acA.x += v0.x; acA.y += v0.y; acA.z += v1.x; acA.w += v1.y;
            acB.x += v2.x; acB.y += v2.y; acB.z += v3.x; acB.w += v3.y;
        }
    }
    // combine the 4 edge groups (dim positions aligned across 16-lane groups)
    acA.x += __shfl_xor(acA.x, 16); acA.x += __shfl_xor(acA.x, 32);
    acA.y += __shfl_xor(acA.y, 16); acA.y += __shfl_xor(acA.y, 32);
    acA.z += __shfl_xor(acA.z, 16); acA.z += __shfl_xor(acA.z, 32);
    acA.w += __shfl_xor(acA.w, 16); acA.w += __shfl_xor(acA.w, 32);
    acB.x += __shfl_xor(acB.x, 16); acB.x += __shfl_xor(acB.x, 32);
    acB.y += __shfl_xor(acB.y, 16); acB.y += __shfl_xor(acB.y, 32);
    acB.z += __shfl_xor(acB.z, 16); acB.z += __shfl_xor(acB.z, 32);
    acB.w += __shfl_xor(acB.w, 16); acB.w += __shfl_xor(acB.w, 32);
    // per-factor l2norm: 4 lanes (il in 4f..4f+3) cover factor f's 32 dims
    float ss = acA.x * acA.x + acA.y * acA.y + acA.z * acA.z + acA.w * acA.w
             + acB.x * acB.x + acB.y * acB.y + acB.z * acB.z + acB.w * acB.w;
    ss += __shfl_xor(ss, 1); ss += __shfl_xor(ss, 2);
    float inv = 1.0f / fmaxf(sqrtf(ss), 1e-12f);
    uint4 au = make_uint4(packh2(acA.x * inv, acA.y * inv),
                          packh2(acA.z * inv, acA.w * inv),
                          packh2(acB.x * inv, acB.y * inv),
                          packh2(acB.z * inv, acB.w * inv));

    // ---- phase B: attention + softmax + deg1 ----
    float dacc = 0.0f;
    #pragma unroll 4
    for (int pb = p0; pb < p1; pb += 4) {
        int p = pb + g;
        if (p < p1) {                                  // group-uniform
            int t = t_sorted[p];
            uint4 bu = ((const uint4*)(ttan + (size_t)t * DD))[il];      // 8 halves
            float s = 0.0f;
            s = fdot2f(au.x, bu.x, s);
            s = fdot2f(au.y, bu.y, s);
            s = fdot2f(au.z, bu.z, s);
            s = fdot2f(au.w, bu.w, s);
            s += __shfl_xor(s, 1);
            s += __shfl_xor(s, 2);                     // 4 lanes of factor f share s_f
            float m1 = fmaxf(s, __shfl_xor(s, 4));
            float mx = fmaxf(m1, __shfl_xor(m1, 8));   // max over 4 factors
            float e = __expf(s - mx);
            float sum = e;
            sum += __shfl_xor(sum, 4);
            sum += __shfl_xor(sum, 8);                 // sum over 4 factors
            float v = e * __builtin_amdgcn_rcpf(sum);  // softmaxed A for factor f
            if (writeA && (il & 3) == 0) normA[(size_t)p * 4 + f] = __float2half(v);
            dacc += v;
        }
    }
    // sum deg over the 4 edge-groups (lane position preserved)
    dacc += __shfl_xor(dacc, 16);
    dacc += __shfl_xor(dacc, 32);
    if (g == 0 && (il & 3) == 0)
        dinv1[(size_t)n * 4 + f] = 1.0f / sqrtf(fmaxf(dacc, 1e-8f));
}

// ---------------- fused iteration-1 propagation + output, batch rows only ----
// out[r] = 0.5*( ego0[n] + dinv1[n][f] * sum_p normA[p][f]*dinv1[t][f]*ego0(t) )
// ego0(t) recovered as inv0[t]*ego16s[t] (fp16 gather, half the bytes).
// 32 lanes per output row (2 rows/wave); lane j covers dims 4j..4j+3, f=j>>3.
__global__ void k_prop1_out(const float* __restrict__ ue, const float* __restrict__ ie,
                            const __half* __restrict__ ego16s,
                            const float* __restrict__ inv0,
                            const int* __restrict__ row_ptr,
                            const unsigned short* __restrict__ t_sorted,
                            const __half* __restrict__ normA, const float* __restrict__ dinv1,
                            const int* __restrict__ users, const int* __restrict__ pos,
                            const int* __restrict__ neg, float* __restrict__ out) {
    int r = blockIdx.x * 8 + (threadIdx.x >> 5);
    if (r >= 3 * NB) return;
    int j = threadIdx.x & 31;
    int f = j >> 3;
    int which = r >> 12;
    int i = r & 4095;
    int n;
    if (which == 0)      n = users[i];
    else if (which == 1) n = NU + pos[i];
    else                 n = NU + neg[i];
    int p0 = row_ptr[n], p1 = row_ptr[n + 1];
    float4 acc = make_float4(0.f, 0.f, 0.f, 0.f);
    #pragma unroll 4
    for (int p = p0; p < p1; ++p) {
        int t = t_sorted[p];
        float w = __half2float(normA[(size_t)p * 4 + f])
                * dinv1[(size_t)t * 4 + f] * inv0[t];
        float2 raw = ((const float2*)(ego16s + (size_t)t * DD))[j];   // 4 halves
        float2 v01 = __half22float2(*(const __half2*)&raw.x);
        float2 v23 = __half22float2(*(const __half2*)&raw.y);
        acc.x += w * v01.x; acc.y += w * v01.y;
        acc.z += w * v23.x; acc.w += w * v23.y;
    }
    float dn = dinv1[(size_t)n * 4 + f];
    float4 e0 = ((const float4*)node_row(ue, ie, n))[j];
    ((float4*)(out + (size_t)r * DD))[j] =
        make_float4(0.5f * (e0.x + dn * acc.x), 0.5f * (e0.y + dn * acc.y),
                    0.5f * (e0.z + dn * acc.z), 0.5f * (e0.w + dn * acc.w));
}

// ---------------- launch ----------------

extern "C" void kernel_launch(void* const* d_in, const int* in_sizes, int n_in,
                              void* d_out, int out_size, void* d_ws, size_t ws_size,
                              hipStream_t stream) {
    const float* ue   = (const float*)d_in[0];
    const float* ie   = (const float*)d_in[1];
    const int* row    = (const int*)d_in[2];
    const int* col    = (const int*)d_in[3];
    const int* users  = (const int*)d_in[4];
    const int* pos    = (const int*)d_in[5];
    const int* neg    = (const int*)d_in[6];
    float* out        = (float*)d_out;

    // workspace layout (256B-aligned); total ~53 MB
    char* ws = (char*)d_ws;
    size_t off = 0;
    auto take = [&](size_t bytes) { void* p = ws + off; off += (bytes + 255) & ~(size_t)255; return p; };
    __half* ttan     = (__half*)take((size_t)NN * DD * 2);   // 15.36 MB (fp16)
    __half* ego16s   = (__half*)take((size_t)NN * DD * 2);   // 15.36 MB (fp16, pre-scaled)
    __half* normA    = (__half*)take((size_t)NE * 4 * 2);    // 9.6 MB (fp16)
    float*  dinv1    = (float*)take((size_t)NN * 4 * 4);     // 0.96 MB
    float*  dinv0    = (float*)take((size_t)NN * 4);         // 0.24 MB
    float*  inv0     = (float*)take((size_t)NN * 4);         // 0.24 MB
    int*    row_ptr  = (int*)take((size_t)(NN + 1) * 4);
    int*    counts   = (int*)take((size_t)NN * CPAD * 4);    // 3.84 MB (padded)
    int*    pre      = (int*)take((size_t)NN * 4);
    int*    bsum     = (int*)take((size_t)NBLK * 4);
    int*    boff     = (int*)take((size_t)NBLK * 4);
    unsigned short* rank     = (unsigned short*)take((size_t)NE * 2);  // 2.4 MB
    unsigned short* t_sorted = (unsigned short*)take((size_t)NE * 2);  // 2.4 MB
    unsigned char*  flags    = (unsigned char*)take((size_t)NN);       // 60 KB
    if (off > ws_size) return;  // workspace too small -> validation flags loudly

    // CSR build (paired edges, padded counters, atomic-free fill)
    k_zero <<<(NN * CPAD + 255) / 256, 256, 0, stream>>>(counts, flags);
    k_flag <<<(3 * NB + 255) / 256, 256, 0, stream>>>(users, pos, neg, flags);
    k_count<<<(ME / 4 + 255) / 256, 256, 0, stream>>>(row, col, counts, rank);
    k_scanA<<<NBLK, 256, 0, stream>>>(counts, pre, bsum);
    k_scanB<<<1, 256, 0, stream>>>(bsum, boff);
    k_scanC<<<NBLK, 256, 0, stream>>>(pre, boff, counts, row_ptr, dinv0, inv0);
    // fp16 tables (pre-scaled ego + tanh(l2norm)) -- needs dinv0
    k_prep <<<(NN * 16 + 255) / 256, 256, 0, stream>>>(ue, ie, dinv0, ego16s, ttan);
    k_fill <<<(ME / 4 + 255) / 256, 256, 0, stream>>>(row, col, row_ptr, rank, t_sorted);
    // fused prop0 + attention + softmax + deg1 (fnorm stays in registers)
    k_mega <<<(NN + 3) / 4, 256, 0, stream>>>(row_ptr, t_sorted, ego16s, ttan,
                                              flags, normA, (float*)dinv1);
    // fused iteration-1 propagation + mean + gather, batch rows only
    k_prop1_out<<<(3 * NB) / 8, 256, 0, stream>>>(ue, ie, ego16s, inv0, row_ptr,
                                                  t_sorted, normA, (const float*)dinv1,
                                                  users, pos, neg, out);
}